// Round 6
// baseline (457.012 us; speedup 1.0000x reference)
//
#include <hip/hip_runtime.h>
#include <stdint.h>

// ---------------------------------------------------------------------------
// Mamba block on MI355X (gfx950).  B=8, L=1024, D_MODEL=512, D_INNER=1024,
// D2=512, DT_RANK=32, N_STATE=16, K_CONV=4, HIDDEN=2048.  M = B*L = 8192.
//
// R6: packed-fragment dataflow (R4) everywhere; the four big GEMMs use
// gemm_wlds: weight column-slab (128 cols x 256 k = 64 KB) resident in LDS,
// refilled K/256 times (2 barriers per refill), and a BARRIER-FREE inner
// K-loop: A-fragments stream from global as contiguous 1 KB loads
// (double-buffered in registers), B-fragments are conflict-free ds_read_b128
// from read-only LDS, 16 MFMAs per k-step. No vmcnt(0) drain in the loop.
// Packed operand layout: (m,k) -> (m/16)*16*K + (k/32)*512 + lane*8 + (k%8),
// lane = ((k>>3)&3)*16 + (m&15).
// ---------------------------------------------------------------------------

#define MROWS 8192
#define LSEQ 1024
#define DMODEL 512
#define DINNER 1024
#define D2 512
#define NSTATE 16
#define HIDDEN 2048
#define NCHUNK 16
#define LCHUNK 64

typedef unsigned short us;
typedef short short8 __attribute__((ext_vector_type(8)));
typedef float floatx4 __attribute__((ext_vector_type(4)));

__device__ __forceinline__ us f2bf(float f) {
    unsigned int u = __float_as_uint(f);
    u = (u + 0x7fffu + ((u >> 16) & 1u)) >> 16;
    return (us)u;
}
__device__ __forceinline__ float bf2f(us u) {
    return __uint_as_float(((unsigned int)u) << 16);
}

__device__ __forceinline__ void g2lds16(const void* g, void* l) {
    typedef __attribute__((address_space(1))) void GV;
    typedef __attribute__((address_space(3))) void LV;
    GV* gp = (GV*)(uintptr_t)g;
    LV* lp = (LV*)(uint32_t)(uintptr_t)l;
    __builtin_amdgcn_global_load_lds(gp, lp, 16, 0, 0);
}

// ---------------------------------------------------------------------------
// Pack fp32 weight W(N,K) -> bf16 fragment order (one 16B slot per sig).
// ---------------------------------------------------------------------------
__device__ __forceinline__ void pack_slot(const float* __restrict__ w,
                                          us* __restrict__ dst, int K, int sig)
{
    int lane = sig & 63;
    int KS = K >> 5;
    int ks = (sig >> 6) % KS;
    int g = sig / (KS << 6);
    const float* src = w + (size_t)(g * 16 + (lane & 15)) * K
                         + ks * 32 + (lane >> 4) * 8;
    short8 o;
    #pragma unroll
    for (int e = 0; e < 8; e++) o[e] = (short)f2bf(src[e]);
    *(short8*)(dst + (size_t)sig * 8) = o;
}

__global__ __launch_bounds__(256) void cvt_pack6(
    const float* __restrict__ w0, const float* __restrict__ w1,
    const float* __restrict__ w2, const float* __restrict__ w3,
    const float* __restrict__ w4, const float* __restrict__ w5,
    us* __restrict__ o0, us* __restrict__ o1, us* __restrict__ o2,
    us* __restrict__ o3, us* __restrict__ o4, us* __restrict__ o5)
{
    int bx = blockIdx.x, t = threadIdx.x;
    if (bx < 256)        pack_slot(w0, o0, 512,  bx * 256 + t);
    else if (bx < 272)   pack_slot(w1, o1, 512,  (bx - 256) * 256 + t);
    else if (bx < 280)   pack_slot(w2, o2, 32,   (bx - 272) * 256 + t);
    else if (bx < 536)   pack_slot(w3, o3, 1024, (bx - 280) * 256 + t);
    else if (bx < 1048)  pack_slot(w4, o4, 512,  (bx - 536) * 256 + t);
    else                 pack_slot(w5, o5, 2048, (bx - 1048) * 256 + t);
}

// ---------------------------------------------------------------------------
// LayerNorm over 512 ch; one block per 16-row group; writes packed bf16.
// ---------------------------------------------------------------------------
__global__ __launch_bounds__(256) void ln_pack(
    const float* __restrict__ x, const float* __restrict__ w,
    const float* __restrict__ b, us* __restrict__ outp)
{
    int g = blockIdx.x, t = threadIdx.x;
    __shared__ float T[16][516];
    __shared__ float mu[16], rs[16];
    const float* src = x + (size_t)g * 16 * DMODEL;
    #pragma unroll
    for (int p = 0; p < 8; p++) {
        int idx4 = p * 256 + t;
        int row = idx4 >> 7, c = (idx4 & 127) << 2;
        float4 v = *(const float4*)(src + (size_t)row * DMODEL + c);
        *(float4*)&T[row][c] = v;
    }
    __syncthreads();
    int r = t >> 4, i = t & 15;
    float s = 0.f, ss = 0.f;
    #pragma unroll
    for (int c = 0; c < 32; c++) {
        float v = T[r][c * 16 + i];
        s += v; ss += v * v;
    }
    #pragma unroll
    for (int off = 8; off > 0; off >>= 1) {
        s += __shfl_down(s, off, 16);
        ss += __shfl_down(ss, off, 16);
    }
    if (i == 0) {
        float m = s * (1.f / DMODEL);
        mu[r] = m;
        rs[r] = rsqrtf(ss * (1.f / DMODEL) - m * m + 1e-5f);
    }
    __syncthreads();
    #pragma unroll
    for (int s0 = 0; s0 < 4; s0++) {
        int sig = t * 4 + s0;
        int lane = sig & 63, ks = sig >> 6;
        int lr = lane & 15, lq = lane >> 4;
        int k0 = ks * 32 + lq * 8;
        float m = mu[lr], r2 = rs[lr];
        short8 o;
        #pragma unroll
        for (int e = 0; e < 8; e++)
            o[e] = (short)f2bf((T[lr][k0 + e] - m) * r2 * w[k0 + e] + b[k0 + e]);
        *(short8*)(outp + (size_t)g * 8192 + sig * 8) = o;
    }
}

#define MO_ROWBF16 0
#define MO_F32_PACK 1
#define MO_SOFTPLUS 2
#define MO_RES 3
#define MO_GELU_PACK 4
#define MO_BIAS_RES 5

// ---------------------------------------------------------------------------
// gemm_wlds: big GEMMs.  C(M,N) = A(M,K) * W(N,K)^T, fp32 acc.
// Block = 128 rows x 128 cols, 4 waves (one 32-row strip each).
// W slab 128x256 (64 KB) resident in LDS, K/256 refills; inner loop has
// NO barriers: A streams from global (reg double-buffer), B from LDS.
// ---------------------------------------------------------------------------
template <int MODE>
__global__ __launch_bounds__(256, 2) void gemm_wlds(
    const us* __restrict__ Ap, const us* __restrict__ Bp, int K,
    int Nout, int ldc,
    float* __restrict__ outF, us* __restrict__ outB, us* __restrict__ outP,
    const float* __restrict__ bias, const float* __restrict__ res)
{
    __shared__ __align__(16) us sW[32768];   // 64 KB: W slab, reused as TT
    int t = threadIdx.x;
    int lane = t & 63, w = t >> 6;
    int lr = lane & 15, lq = lane >> 4;
    int m0 = blockIdx.x * 128, n0 = blockIdx.y * 128;
    int gB0 = blockIdx.y * 8;
    const int NK = K >> 8;

    floatx4 acc[2][8];
    #pragma unroll
    for (int i = 0; i < 2; i++)
        #pragma unroll
        for (int j = 0; j < 8; j++) acc[i][j] = (floatx4){0.f, 0.f, 0.f, 0.f};

    const us* Abase0 = Ap + ((size_t)(blockIdx.x * 8 + w * 2) * K) * 16 + lane * 8;
    const us* Abase1 = Abase0 + (size_t)K * 16;

    for (int ph = 0; ph < NK; ph++) {
        // refill W slab: 64 x 1KB slots, 16 per wave
        #pragma unroll
        for (int s = 0; s < 16; s++) {
            int slot = w * 16 + s;
            int j = slot >> 3, kl = slot & 7;
            g2lds16(Bp + ((size_t)(gB0 + j) * K + ph * 256 + kl * 32) * 16 + lane * 8,
                    sW + slot * 512);
        }
        __syncthreads();

        short8 afb[2][2];
        afb[0][0] = *(const short8*)(Abase0 + (size_t)ph * 4096);
        afb[0][1] = *(const short8*)(Abase1 + (size_t)ph * 4096);
        #pragma unroll
        for (int kl = 0; kl < 8; kl++) {
            if (kl < 7) {
                afb[(kl + 1) & 1][0] =
                    *(const short8*)(Abase0 + (size_t)ph * 4096 + (kl + 1) * 512);
                afb[(kl + 1) & 1][1] =
                    *(const short8*)(Abase1 + (size_t)ph * 4096 + (kl + 1) * 512);
            }
            short8 bf[8];
            #pragma unroll
            for (int j = 0; j < 8; j++)
                bf[j] = *(const short8*)(sW + (j * 8 + kl) * 512 + lane * 8);
            #pragma unroll
            for (int i = 0; i < 2; i++)
                #pragma unroll
                for (int j = 0; j < 8; j++)
                    acc[i][j] = __builtin_amdgcn_mfma_f32_16x16x32_bf16(
                        afb[kl & 1][i], bf[j], acc[i][j], 0, 0, 0);
        }
        __syncthreads();   // slab dead; safe to refill / reuse as TT
    }

    // ---- epilogue: dump acc to TT (row-major f32 tile), then write out ----
    float (*TT)[128] = (float (*)[128])sW;
    #pragma unroll
    for (int i = 0; i < 2; i++)
        #pragma unroll
        for (int j = 0; j < 8; j++)
            #pragma unroll
            for (int r = 0; r < 4; r++)
                TT[w * 32 + i * 16 + lq * 4 + r][j * 16 + lr] = acc[i][j][r];
    __syncthreads();

    if (MODE == MO_ROWBF16) {
        #pragma unroll
        for (int p = 0; p < 8; p++) {
            int idx = p * 256 + t;
            int row = idx >> 4, c = (idx & 15) << 3;
            short8 o8;
            #pragma unroll
            for (int e = 0; e < 8; e++) o8[e] = (short)f2bf(TT[row][c + e]);
            *(short8*)(outB + (size_t)(m0 + row) * ldc + n0 + c) = o8;
        }
    }
    if (MODE == MO_RES || MODE == MO_BIAS_RES) {
        #pragma unroll
        for (int p = 0; p < 16; p++) {
            int idx = p * 256 + t;
            int row = idx >> 5, c = (idx & 31) << 2;
            float4 v = *(float4*)&TT[row][c];
            int col = n0 + c;
            size_t o = (size_t)(m0 + row) * ldc + col;
            float4 rv = *(const float4*)(res + o);
            float4 ov;
            if (MODE == MO_BIAS_RES) {
                float4 bv = *(const float4*)(bias + col);
                ov.x = v.x + bv.x + rv.x; ov.y = v.y + bv.y + rv.y;
                ov.z = v.z + bv.z + rv.z; ov.w = v.w + bv.w + rv.w;
            } else {
                ov.x = v.x + rv.x; ov.y = v.y + rv.y;
                ov.z = v.z + rv.z; ov.w = v.w + rv.w;
            }
            *(float4*)(outF + o) = ov;
        }
    }
    if (MODE == MO_GELU_PACK) {
        #pragma unroll
        for (int p = 0; p < 8; p++) {
            int sig = p * 256 + t;
            int gi = sig >> 8;
            int rem = sig & 255;
            int ksl = rem >> 6;
            int ln2 = rem & 63;
            int lr2 = ln2 & 15, lq2 = ln2 >> 4;
            short8 o8;
            #pragma unroll
            for (int e = 0; e < 8; e++) {
                int colg = n0 + ksl * 32 + lq2 * 8 + e;
                float tb = TT[gi * 16 + lr2][ksl * 32 + lq2 * 8 + e] + bias[colg];
                float vv = 0.5f * tb * (1.f + erff(tb * 0.70710678118f));
                o8[e] = (short)f2bf(vv);
            }
            *(short8*)(outP + ((size_t)((m0 >> 4) + gi) * Nout + n0 + ksl * 32) * 16
                       + ln2 * 8) = o8;
        }
    }
}

// ---------------------------------------------------------------------------
// gemm_pk (R4, BM=64/BN=64): small GEMMs (x_proj, dt_proj).
// ---------------------------------------------------------------------------
template <int MODE, int BN>
__global__ __launch_bounds__(256) void gemm_pk(
    const us* __restrict__ Ap, int KA,
    const us* __restrict__ Bp, int KB, int Kloop,
    int Nout, int ldc,
    float* __restrict__ outF, us* __restrict__ outB, us* __restrict__ outP,
    const float* __restrict__ bias, const float* __restrict__ res)
{
    constexpr int NBg = BN / 16;
    constexpr int NJ = BN / 32;
    constexpr int TS = 4 + NBg;
    constexpr int PS = TS / 4;
    constexpr int SMSZ = 64 * (BN + 4) * 4;
    __shared__ __align__(16) char smraw[SMSZ];
    us* sA = (us*)smraw;
    us* sB = sA + 2048;
    float (*TT)[BN + 4] = (float (*)[BN + 4])smraw;

    int t = threadIdx.x;
    int lane = t & 63, w = t >> 6;
    int lr = lane & 15, lq = lane >> 4;
    int m0 = blockIdx.x * 64, n0 = blockIdx.y * BN;
    int gA0 = blockIdx.x * 4;
    int gB0 = n0 >> 4;

    floatx4 acc[2][NJ];
    #pragma unroll
    for (int i = 0; i < 2; i++)
        #pragma unroll
        for (int j = 0; j < NJ; j++) acc[i][j] = (floatx4){0.f, 0.f, 0.f, 0.f};

    for (int ks = 0; ks * 32 < Kloop; ks++) {
        #pragma unroll
        for (int s = 0; s < PS; s++) {
            int slot = w * PS + s;
            if (slot < 4)
                g2lds16(Ap + ((size_t)(gA0 + slot) * KA + ks * 32) * 16 + lane * 8,
                        sA + slot * 512);
            else
                g2lds16(Bp + ((size_t)(gB0 + slot - 4) * KB + ks * 32) * 16 + lane * 8,
                        sB + (slot - 4) * 512);
        }
        __syncthreads();
        short8 af[2], bfv[NJ];
        #pragma unroll
        for (int i = 0; i < 2; i++)
            af[i] = *(const short8*)(sA + ((w & 1) * 2 + i) * 512 + lane * 8);
        #pragma unroll
        for (int j = 0; j < NJ; j++)
            bfv[j] = *(const short8*)(sB + ((w >> 1) * NJ + j) * 512 + lane * 8);
        #pragma unroll
        for (int i = 0; i < 2; i++)
            #pragma unroll
            for (int j = 0; j < NJ; j++)
                acc[i][j] = __builtin_amdgcn_mfma_f32_16x16x32_bf16(
                    af[i], bfv[j], acc[i][j], 0, 0, 0);
        __syncthreads();
    }

    #pragma unroll
    for (int i = 0; i < 2; i++)
        #pragma unroll
        for (int j = 0; j < NJ; j++)
            #pragma unroll
            for (int r = 0; r < 4; r++)
                TT[(w & 1) * 32 + i * 16 + lq * 4 + r]
                  [(w >> 1) * (BN / 2) + j * 16 + lr] = acc[i][j][r];
    __syncthreads();

    if (MODE == MO_F32_PACK || MODE == MO_SOFTPLUS) {
        constexpr int passes = 64 * BN / 4 / 256;
        #pragma unroll
        for (int p = 0; p < passes; p++) {
            int idx = p * 256 + t;
            int row = idx / (BN / 4);
            int c = (idx % (BN / 4)) * 4;
            float4 v = *(float4*)&TT[row][c];
            int col = n0 + c;
            size_t o = (size_t)(m0 + row) * ldc + col;
            float vv[4] = {v.x, v.y, v.z, v.w};
            float oo[4];
            #pragma unroll
            for (int e = 0; e < 4; e++) {
                if (MODE == MO_SOFTPLUS) {
                    float tb = vv[e] + bias[col + e];
                    oo[e] = (tb > 20.f) ? tb : log1pf(__expf(tb));
                } else {
                    oo[e] = vv[e];
                }
            }
            float4 ov = {oo[0], oo[1], oo[2], oo[3]};
            *(float4*)(outF + o) = ov;
        }
    }
    if (MODE == MO_F32_PACK) {
        constexpr int passes = 8 * BN / 256;
        #pragma unroll
        for (int p = 0; p < passes; p++) {
            int sig = p * 256 + t;
            int gi = sig / (2 * BN);
            int rem = sig % (2 * BN);
            int ksl = rem >> 6;
            int ln2 = rem & 63;
            int lr2 = ln2 & 15, lq2 = ln2 >> 4;
            short8 o8;
            #pragma unroll
            for (int e = 0; e < 8; e++)
                o8[e] = (short)f2bf(TT[gi * 16 + lr2][ksl * 32 + lq2 * 8 + e]);
            *(short8*)(outP + ((size_t)((m0 >> 4) + gi) * Nout + n0 + ksl * 32) * 16
                       + ln2 * 8) = o8;
        }
    }
}

// ---------------------------------------------------------------------------
// Depthwise conv (K=4, pad 1/2) + SiLU; writes packed xh / z and xh f32 rows.
// ---------------------------------------------------------------------------
__global__ __launch_bounds__(256) void conv_pk(
    const us* __restrict__ xz, const float* __restrict__ cwx,
    const float* __restrict__ cwz, float* __restrict__ xh_f,
    us* __restrict__ xh_p, us* __restrict__ outbuf_p)
{
    int bx = blockIdx.x, t = threadIdx.x;
    int b = bx >> 6, g = bx & 63;
    size_t rowbase = (size_t)b * LSEQ;
    #pragma unroll
    for (int s = 0; s < 4; s++) {
        int sig = t * 4 + s;
        int ks = sig >> 6, lane = sig & 63;
        int lr = lane & 15, lq = lane >> 4;
        int l = g * 16 + lr;
        int d0 = ks * 32 + lq * 8;
        float ax[8] = {0, 0, 0, 0, 0, 0, 0, 0};
        #pragma unroll
        for (int kk = 0; kk < 4; kk++) {
            int ls = l + kk - 1;
            if (ls >= 0 && ls < LSEQ) {
                const us* src = xz + (rowbase + ls) * DINNER + d0;
                #pragma unroll
                for (int e = 0; e < 8; e++)
                    ax[e] += cwx[(d0 + e) * 4 + kk] * bf2f(src[e]);
            }
        }
        short8 o8;
        float vo[8];
        #pragma unroll
        for (int e = 0; e < 8; e++) {
            float v = ax[e];
            v = v / (1.f + __expf(-v));
            vo[e] = v;
            o8[e] = (short)f2bf(v);
        }
        *(short8*)(xh_p + (size_t)bx * 8192 + sig * 8) = o8;
        float* fo = xh_f + (rowbase + l) * D2 + d0;
        float4 f0 = {vo[0], vo[1], vo[2], vo[3]};
        float4 f1 = {vo[4], vo[5], vo[6], vo[7]};
        *(float4*)fo = f0;
        *(float4*)(fo + 4) = f1;
    }
    #pragma unroll
    for (int s = 0; s < 4; s++) {
        int sig = t * 4 + s;
        int ks = sig >> 6, lane = sig & 63;
        int lr = lane & 15, lq = lane >> 4;
        int l = g * 16 + lr;
        int d0 = ks * 32 + lq * 8;
        float az[8] = {0, 0, 0, 0, 0, 0, 0, 0};
        #pragma unroll
        for (int kk = 0; kk < 4; kk++) {
            int ls = l + kk - 1;
            if (ls >= 0 && ls < LSEQ) {
                const us* src = xz + (rowbase + ls) * DINNER + 512 + d0;
                #pragma unroll
                for (int e = 0; e < 8; e++)
                    az[e] += cwz[(d0 + e) * 4 + kk] * bf2f(src[e]);
            }
        }
        short8 o8;
        #pragma unroll
        for (int e = 0; e < 8; e++) {
            float v = az[e];
            v = v / (1.f + __expf(-v));
            o8[e] = (short)f2bf(v);
        }
        *(short8*)(outbuf_p + (size_t)bx * 16384 + 8192 + sig * 8) = o8;
    }
}

// ---------------------------------------------------------------------------
// Selective scan, 3-phase chunked linear recurrence (phase3 writes packed y).
// ---------------------------------------------------------------------------
__global__ __launch_bounds__(256) void scan_phase1(
    const float* __restrict__ delta, const float* __restrict__ u,
    const float* __restrict__ xdbl, const float* __restrict__ A_log,
    float* __restrict__ S, float* __restrict__ P)
{
    int bx = blockIdx.x;
    int b = bx >> 5, rem = bx & 31, c = rem >> 1, half = rem & 1;
    int d = half * 256 + threadIdx.x;
    float A[NSTATE], h[NSTATE];
    #pragma unroll
    for (int n = 0; n < NSTATE; n++) {
        A[n] = -__expf(A_log[d * NSTATE + n]);
        h[n] = 0.f;
    }
    float sdt = 0.f;
    int l0 = c * LCHUNK;
    for (int l = l0; l < l0 + LCHUNK; ++l) {
        size_t idx = (size_t)(b * LSEQ + l);
        float dv = delta[idx * D2 + d];
        float uv = u[idx * D2 + d];
        float du = dv * uv;
        const float4* Bp = (const float4*)(xdbl + idx * 64 + 32);
        float4 B0 = Bp[0], B1 = Bp[1], B2 = Bp[2], B3 = Bp[3];
        float Bn[16] = {B0.x, B0.y, B0.z, B0.w, B1.x, B1.y, B1.z, B1.w,
                        B2.x, B2.y, B2.z, B2.w, B3.x, B3.y, B3.z, B3.w};
        sdt += dv;
        #pragma unroll
        for (int n = 0; n < NSTATE; n++)
            h[n] = __expf(dv * A[n]) * h[n] + du * Bn[n];
    }
    size_t o = ((size_t)(b * D2 + d)) * (NCHUNK * NSTATE) + c * NSTATE;
    #pragma unroll
    for (int n = 0; n < NSTATE; n++) {
        S[o + n] = h[n];
        P[o + n] = __expf(sdt * A[n]);
    }
}

__global__ __launch_bounds__(256) void scan_phase2(
    const float* __restrict__ S, const float* __restrict__ P,
    float* __restrict__ hin)
{
    int gid = blockIdx.x * 256 + threadIdx.x;
    int n = gid & 15;
    size_t base = ((size_t)(gid >> 4)) * (NCHUNK * NSTATE) + n;
    float h = 0.f;
    for (int c = 0; c < NCHUNK; c++) {
        size_t o = base + c * NSTATE;
        hin[o] = h;
        h = P[o] * h + S[o];
    }
}

__global__ __launch_bounds__(256) void scan_phase3(
    const float* __restrict__ delta, const float* __restrict__ u,
    const float* __restrict__ xdbl, const float* __restrict__ hin,
    const float* __restrict__ A_log, const float* __restrict__ Dvec,
    us* __restrict__ outbuf_p)
{
    int bx = blockIdx.x;
    int b = bx >> 5, rem = bx & 31, c = rem >> 1, half = rem & 1;
    int t = threadIdx.x;
    int d = half * 256 + t;
    __shared__ us yl[64][264];
    float A[NSTATE], h[NSTATE];
    size_t hb = ((size_t)(b * D2 + d)) * (NCHUNK * NSTATE) + c * NSTATE;
    #pragma unroll
    for (int n = 0; n < NSTATE; n++) {
        A[n] = -__expf(A_log[d * NSTATE + n]);
        h[n] = hin[hb + n];
    }
    float Dd = Dvec[d];
    int l0 = c * LCHUNK;
    for (int l = l0; l < l0 + LCHUNK; ++l) {
        size_t idx = (size_t)(b * LSEQ + l);
        float dv = delta[idx * D2 + d];
        float uv = u[idx * D2 + d];
        float du = dv * uv;
        const float4* Bp = (const float4*)(xdbl + idx * 64 + 32);
        const float4* Cp = (const float4*)(xdbl + idx * 64 + 48);
        float4 B0 = Bp[0], B1 = Bp[1], B2 = Bp[2], B3 = Bp[3];
        float4 C0 = Cp[0], C1 = Cp[1], C2 = Cp[2], C3 = Cp[3];
        float Bn[16] = {B0.x, B0.y, B0.z, B0.w, B1.x, B1.y, B1.z, B1.w,
                        B2.x, B2.y, B2.z, B2.w, B3.x, B3.y, B3.z, B3.w};
        float Cn[16] = {C0.x, C0.y, C0.z, C0.w, C1.x, C1.y, C1.z, C1.w,
                        C2.x, C2.y, C2.z, C2.w, C3.x, C3.y, C3.z, C3.w};
        float y = Dd * uv;
        #pragma unroll
        for (int n = 0; n < NSTATE; n++) {
            h[n] = __expf(dv * A[n]) * h[n] + du * Bn[n];
            y += h[n] * Cn[n];
        }
        yl[l - l0][t] = f2bf(y);
    }
    __syncthreads();
    int g0 = (b * LSEQ + l0) >> 4;
    #pragma unroll
    for (int s = 0; s < 8; s++) {
        int sig = t * 8 + s;
        int gi = sig >> 9;
        int rem2 = sig & 511;
        int ksl = rem2 >> 6;
        int lane = rem2 & 63;
        int lr = lane & 15, lq = lane >> 4;
        uint4 v = *(uint4*)&yl[gi * 16 + lr][ksl * 32 + lq * 8];
        *(uint4*)(outbuf_p + ((size_t)(g0 + gi) * 1024 + (half * 8 + ksl) * 32) * 16
                  + lane * 8) = v;
    }
}

// ---------------------------------------------------------------------------
// Host-side launch
// ---------------------------------------------------------------------------
extern "C" void kernel_launch(void* const* d_in, const int* in_sizes, int n_in,
                              void* d_out, int out_size, void* d_ws, size_t ws_size,
                              hipStream_t stream)
{
    const float* x         = (const float*)d_in[0];
    const float* ln1_w     = (const float*)d_in[1];
    const float* ln1_b     = (const float*)d_in[2];
    const float* in_proj_w = (const float*)d_in[3];
    const float* conv_x_w  = (const float*)d_in[4];
    const float* conv_z_w  = (const float*)d_in[5];
    const float* x_proj_w  = (const float*)d_in[6];
    const float* dt_proj_w = (const float*)d_in[7];
    const float* dt_proj_b = (const float*)d_in[8];
    const float* A_log     = (const float*)d_in[9];
    const float* ssm_D     = (const float*)d_in[10];
    const float* out_proj_w= (const float*)d_in[11];
    const float* ln2_w     = (const float*)d_in[12];
    const float* ln2_b     = (const float*)d_in[13];
    const float* fc1_w     = (const float*)d_in[14];
    const float* fc1_b     = (const float*)d_in[15];
    const float* fc2_w     = (const float*)d_in[16];
    const float* fc2_b     = (const float*)d_in[17];
    float* out = (float*)d_out;

    char* p = (char*)d_ws;
    us* wp_in  = (us*)(p);
    us* wp_x   = (us*)(p + 1048576);
    us* wp_dt  = (us*)(p + 1114112);
    us* wp_out = (us*)(p + 1146880);
    us* wp_f1  = (us*)(p + 2195456);
    us* wp_f2  = (us*)(p + 4292608);
    us*    xn_p    = (us*)(p + 6389760);
    us*    xz      = (us*)(p + 14778368);
    us*    xh_p    = (us*)(p + 31555584);
    float* xh_f    = (float*)(p + 39944192);
    us*    outbuf_p= (us*)(p + 56721408);
    float* xdbl_f  = (float*)(p + 73498624);
    us*    xdbl_p  = (us*)(p + 75595776);
    float* delta_f = (float*)(p + 76644352);
    float* scanS   = (float*)(p + 93421568);
    float* scanP   = (float*)(p + 97615872);
    float* hin     = (float*)(p + 101810176);
    float* h_f     = (float*)(p + 106004480);
    us*    h2_p    = xn_p;
    us*    mlp1_p  = xz;

    // 1. weights -> packed bf16
    cvt_pack6<<<1560, 256, 0, stream>>>(in_proj_w, x_proj_w, dt_proj_w,
        out_proj_w, fc1_w, fc2_w, wp_in, wp_x, wp_dt, wp_out, wp_f1, wp_f2);

    // 2. LN1 -> xn packed
    ln_pack<<<512, 256, 0, stream>>>(x, ln1_w, ln1_b, xn_p);

    // 3. in_proj (8192x1024, K=512) -> xz row-major bf16
    gemm_wlds<MO_ROWBF16><<<dim3(64, 8), 256, 0, stream>>>(
        xn_p, wp_in, 512, 0, DINNER, nullptr, xz, nullptr, nullptr, nullptr);

    // 4. conv + SiLU -> xh (f32 row + packed), z -> outbuf packed (k>=512)
    conv_pk<<<512, 256, 0, stream>>>(xz, conv_x_w, conv_z_w, xh_f, xh_p, outbuf_p);

    // 5. x_proj (8192x64, K=512) -> xdbl f32 row + packed bf16 (Kpack=64)
    gemm_pk<MO_F32_PACK, 64><<<dim3(128, 1), 256, 0, stream>>>(
        xh_p, 512, wp_x, 512, 512, 64, 64,
        xdbl_f, nullptr, xdbl_p, nullptr, nullptr);

    // 6. dt_proj (8192x512, K=32) + softplus -> delta f32 row-major
    gemm_pk<MO_SOFTPLUS, 64><<<dim3(128, 8), 256, 0, stream>>>(
        xdbl_p, 64, wp_dt, 32, 32, 0, D2,
        delta_f, nullptr, nullptr, dt_proj_b, nullptr);

    // 7-9. selective scan; phase3 writes y packed into outbuf (k<512)
    scan_phase1<<<256, 256, 0, stream>>>(delta_f, xh_f, xdbl_f, A_log, scanS, scanP);
    scan_phase2<<<256, 256, 0, stream>>>(scanS, scanP, hin);
    scan_phase3<<<512, 256, 0, stream>>>(delta_f, xh_f, xdbl_f, hin, A_log,
        ssm_D, outbuf_p);

    // 10. out_proj (8192x512, K=1024) + residual x -> h f32 row-major
    gemm_wlds<MO_RES><<<dim3(64, 4), 256, 0, stream>>>(
        outbuf_p, wp_out, 1024, 0, DMODEL, h_f, nullptr, nullptr, nullptr, x);

    // 11. LN2 -> h2 packed
    ln_pack<<<512, 256, 0, stream>>>(h_f, ln2_w, ln2_b, h2_p);

    // 12. fc1 (8192x2048, K=512) + bias + GELU -> mlp1 packed (Kpack=2048)
    gemm_wlds<MO_GELU_PACK><<<dim3(64, 16), 256, 0, stream>>>(
        h2_p, wp_f1, 512, HIDDEN, 0, nullptr, nullptr, mlp1_p, fc1_b, nullptr);

    // 13. fc2 (8192x512, K=2048) + bias + residual h -> d_out f32
    gemm_wlds<MO_BIAS_RES><<<dim3(64, 4), 256, 0, stream>>>(
        mlp1_p, wp_f2, 2048, 0, DMODEL, out, nullptr, nullptr, fc2_b, h_f);
}

// Round 7
// 384.646 us; speedup vs baseline: 1.1881x; 1.1881x over previous
//
#include <hip/hip_runtime.h>
#include <stdint.h>

// ---------------------------------------------------------------------------
// Mamba block on MI355X (gfx950).  B=8, L=1024, D_MODEL=512, D_INNER=1024,
// D2=512, DT_RANK=32, N_STATE=16, K_CONV=4, HIDDEN=2048.  M = B*L = 8192.
//
// R7: big GEMMs = gemm_rd: packed-fragment operands loaded DIRECTLY to
// registers (one contiguous 1 KB global_load per fragment), 4-deep rotating
// register pipeline -> no LDS, no barriers, no vmcnt(0) in the K-loop.
// Wave-private LDS transpose only in the epilogue (stride 68, one barrier).
// Packed operand layout: (m,k) -> (m/16)*16*K + (k/32)*512 + lane*8 + (k%8),
// lane = ((k>>3)&3)*16 + (m&15).
// ---------------------------------------------------------------------------

#define MROWS 8192
#define LSEQ 1024
#define DMODEL 512
#define DINNER 1024
#define D2 512
#define NSTATE 16
#define HIDDEN 2048
#define NCHUNK 16
#define LCHUNK 64

typedef unsigned short us;
typedef short short8 __attribute__((ext_vector_type(8)));
typedef float floatx4 __attribute__((ext_vector_type(4)));

__device__ __forceinline__ us f2bf(float f) {
    unsigned int u = __float_as_uint(f);
    u = (u + 0x7fffu + ((u >> 16) & 1u)) >> 16;
    return (us)u;
}
__device__ __forceinline__ float bf2f(us u) {
    return __uint_as_float(((unsigned int)u) << 16);
}

__device__ __forceinline__ void g2lds16(const void* g, void* l) {
    typedef __attribute__((address_space(1))) void GV;
    typedef __attribute__((address_space(3))) void LV;
    GV* gp = (GV*)(uintptr_t)g;
    LV* lp = (LV*)(uint32_t)(uintptr_t)l;
    __builtin_amdgcn_global_load_lds(gp, lp, 16, 0, 0);
}

// ---------------------------------------------------------------------------
// Pack fp32 weight W(N,K) -> bf16 fragment order (one 16B slot per sig).
// ---------------------------------------------------------------------------
__device__ __forceinline__ void pack_slot(const float* __restrict__ w,
                                          us* __restrict__ dst, int K, int sig)
{
    int lane = sig & 63;
    int KS = K >> 5;
    int ks = (sig >> 6) % KS;
    int g = sig / (KS << 6);
    const float* src = w + (size_t)(g * 16 + (lane & 15)) * K
                         + ks * 32 + (lane >> 4) * 8;
    short8 o;
    #pragma unroll
    for (int e = 0; e < 8; e++) o[e] = (short)f2bf(src[e]);
    *(short8*)(dst + (size_t)sig * 8) = o;
}

__global__ __launch_bounds__(256) void cvt_pack6(
    const float* __restrict__ w0, const float* __restrict__ w1,
    const float* __restrict__ w2, const float* __restrict__ w3,
    const float* __restrict__ w4, const float* __restrict__ w5,
    us* __restrict__ o0, us* __restrict__ o1, us* __restrict__ o2,
    us* __restrict__ o3, us* __restrict__ o4, us* __restrict__ o5)
{
    int bx = blockIdx.x, t = threadIdx.x;
    if (bx < 256)        pack_slot(w0, o0, 512,  bx * 256 + t);
    else if (bx < 272)   pack_slot(w1, o1, 512,  (bx - 256) * 256 + t);
    else if (bx < 280)   pack_slot(w2, o2, 32,   (bx - 272) * 256 + t);
    else if (bx < 536)   pack_slot(w3, o3, 1024, (bx - 280) * 256 + t);
    else if (bx < 1048)  pack_slot(w4, o4, 512,  (bx - 536) * 256 + t);
    else                 pack_slot(w5, o5, 2048, (bx - 1048) * 256 + t);
}

// ---------------------------------------------------------------------------
// LayerNorm over 512 ch; one block per 16-row group; writes packed bf16.
// ---------------------------------------------------------------------------
__global__ __launch_bounds__(256) void ln_pack(
    const float* __restrict__ x, const float* __restrict__ w,
    const float* __restrict__ b, us* __restrict__ outp)
{
    int g = blockIdx.x, t = threadIdx.x;
    __shared__ float T[16][516];
    __shared__ float mu[16], rs[16];
    const float* src = x + (size_t)g * 16 * DMODEL;
    #pragma unroll
    for (int p = 0; p < 8; p++) {
        int idx4 = p * 256 + t;
        int row = idx4 >> 7, c = (idx4 & 127) << 2;
        float4 v = *(const float4*)(src + (size_t)row * DMODEL + c);
        *(float4*)&T[row][c] = v;
    }
    __syncthreads();
    int r = t >> 4, i = t & 15;
    float s = 0.f, ss = 0.f;
    #pragma unroll
    for (int c = 0; c < 32; c++) {
        float v = T[r][c * 16 + i];
        s += v; ss += v * v;
    }
    #pragma unroll
    for (int off = 8; off > 0; off >>= 1) {
        s += __shfl_down(s, off, 16);
        ss += __shfl_down(ss, off, 16);
    }
    if (i == 0) {
        float m = s * (1.f / DMODEL);
        mu[r] = m;
        rs[r] = rsqrtf(ss * (1.f / DMODEL) - m * m + 1e-5f);
    }
    __syncthreads();
    #pragma unroll
    for (int s0 = 0; s0 < 4; s0++) {
        int sig = t * 4 + s0;
        int lane = sig & 63, ks = sig >> 6;
        int lr = lane & 15, lq = lane >> 4;
        int k0 = ks * 32 + lq * 8;
        float m = mu[lr], r2 = rs[lr];
        short8 o;
        #pragma unroll
        for (int e = 0; e < 8; e++)
            o[e] = (short)f2bf((T[lr][k0 + e] - m) * r2 * w[k0 + e] + b[k0 + e]);
        *(short8*)(outp + (size_t)g * 8192 + sig * 8) = o;
    }
}

#define MO_ROWBF16 0
#define MO_F32_PACK 1
#define MO_SOFTPLUS 2
#define MO_RES 3
#define MO_GELU_PACK 4
#define MO_BIAS_RES 5

// ---------------------------------------------------------------------------
// gemm_rd: big GEMMs.  C(M,N) = A(M,K) * W(N,K)^T, fp32 acc.
// 4 waves per block stacked in M; each wave owns WM x 64 output.
// K-loop: direct global->register packed-fragment loads, 4-deep rotating
// buffers, zero barriers/LDS. K/32 must be a multiple of 4.
// ---------------------------------------------------------------------------
template <int MODE, int WM>
__global__ __launch_bounds__(256) void gemm_rd(
    const us* __restrict__ Ap, const us* __restrict__ Bp, int K,
    int Nout, int ldc,
    float* __restrict__ outF, us* __restrict__ outB, us* __restrict__ outP,
    const float* __restrict__ bias, const float* __restrict__ res)
{
    constexpr int AI = WM / 16;
    constexpr int TTW = 68;
    __shared__ float TT[4][WM][TTW];
    int t = threadIdx.x, lane = t & 63, w = t >> 6;
    int lr = lane & 15, lq = lane >> 4;
    int KS = K >> 5;
    int m0 = (blockIdx.x * 4 + w) * WM;
    int n0 = blockIdx.y * 64;
    const us* Ab = Ap + ((size_t)(m0 >> 4) * KS) * 512 + lane * 8;
    const us* Bb = Bp + ((size_t)(n0 >> 4) * KS) * 512 + lane * 8;

    floatx4 acc[AI][4];
    #pragma unroll
    for (int i = 0; i < AI; i++)
        #pragma unroll
        for (int j = 0; j < 4; j++) acc[i][j] = (floatx4){0.f, 0.f, 0.f, 0.f};

    short8 abf[4][AI], bbf[4][4];
    auto ld = [&](int ks, int buf) {
        #pragma unroll
        for (int i = 0; i < AI; i++)
            abf[buf][i] = *(const short8*)(Ab + ((size_t)i * KS + ks) * 512);
        #pragma unroll
        for (int j = 0; j < 4; j++)
            bbf[buf][j] = *(const short8*)(Bb + ((size_t)j * KS + ks) * 512);
    };
    auto mm = [&](int buf) {
        #pragma unroll
        for (int i = 0; i < AI; i++)
            #pragma unroll
            for (int j = 0; j < 4; j++)
                acc[i][j] = __builtin_amdgcn_mfma_f32_16x16x32_bf16(
                    abf[buf][i], bbf[buf][j], acc[i][j], 0, 0, 0);
    };

    const int T = KS;              // 16 / 32 / 64 here (multiple of 4, >= 4)
    ld(0, 0); ld(1, 1); ld(2, 2);
    int tt = 0;
    for (; tt + 7 <= T; tt += 4) {
        ld(tt + 3, 3); mm(0);
        ld(tt + 4, 0); mm(1);
        ld(tt + 5, 1); mm(2);
        ld(tt + 6, 2); mm(3);
    }
    // here T - tt == 4 and buffers 0,1,2 hold steps tt, tt+1, tt+2
    ld(T - 1, 3);
    mm(0); mm(1); mm(2); mm(3);

    // ---- epilogue: wave-private transpose then coalesced/packed stores ----
    #pragma unroll
    for (int i = 0; i < AI; i++)
        #pragma unroll
        for (int j = 0; j < 4; j++)
            #pragma unroll
            for (int r = 0; r < 4; r++)
                TT[w][i * 16 + lq * 4 + r][j * 16 + lr] = acc[i][j][r];
    __syncthreads();

    if (MODE == MO_ROWBF16) {
        #pragma unroll
        for (int p = 0; p < WM / 8; p++) {
            int row = p * 8 + (lane >> 3);
            int c = (lane & 7) * 8;
            short8 o8;
            #pragma unroll
            for (int e = 0; e < 8; e++) o8[e] = (short)f2bf(TT[w][row][c + e]);
            *(short8*)(outB + (size_t)(m0 + row) * ldc + n0 + c) = o8;
        }
    }
    if (MODE == MO_RES || MODE == MO_BIAS_RES) {
        #pragma unroll
        for (int p = 0; p < WM / 4; p++) {
            int row = p * 4 + (lane >> 4);
            int c = (lane & 15) * 4;
            float4 v = *(float4*)&TT[w][row][c];
            int col = n0 + c;
            size_t o = (size_t)(m0 + row) * ldc + col;
            float4 rv = *(const float4*)(res + o);
            float4 ov;
            if (MODE == MO_BIAS_RES) {
                float4 bv = *(const float4*)(bias + col);
                ov.x = v.x + bv.x + rv.x; ov.y = v.y + bv.y + rv.y;
                ov.z = v.z + bv.z + rv.z; ov.w = v.w + bv.w + rv.w;
            } else {
                ov.x = v.x + rv.x; ov.y = v.y + rv.y;
                ov.z = v.z + rv.z; ov.w = v.w + rv.w;
            }
            *(float4*)(outF + o) = ov;
        }
    }
    if (MODE == MO_GELU_PACK) {
        #pragma unroll
        for (int gi = 0; gi < AI; gi++) {
            #pragma unroll
            for (int ks = 0; ks < 2; ks++) {
                short8 o8;
                #pragma unroll
                for (int e = 0; e < 8; e++) {
                    int nloc = ks * 32 + lq * 8 + e;
                    float tb = TT[w][gi * 16 + lr][nloc] + bias[n0 + nloc];
                    float vv = 0.5f * tb * (1.f + erff(tb * 0.70710678118f));
                    o8[e] = (short)f2bf(vv);
                }
                *(short8*)(outP + ((size_t)((m0 >> 4) + gi) * (Nout >> 5)
                           + (n0 >> 5) + ks) * 512 + lane * 8) = o8;
            }
        }
    }
}

// ---------------------------------------------------------------------------
// gemm_pk (R4, BM=64): small GEMMs (x_proj, dt_proj).
// ---------------------------------------------------------------------------
template <int MODE, int BN>
__global__ __launch_bounds__(256) void gemm_pk(
    const us* __restrict__ Ap, int KA,
    const us* __restrict__ Bp, int KB, int Kloop,
    int Nout, int ldc,
    float* __restrict__ outF, us* __restrict__ outB, us* __restrict__ outP,
    const float* __restrict__ bias, const float* __restrict__ res)
{
    constexpr int NBg = BN / 16;
    constexpr int NJ = BN / 32;
    constexpr int TS = 4 + NBg;
    constexpr int PS = TS / 4;
    constexpr int SMSZ = 64 * (BN + 4) * 4;
    __shared__ __align__(16) char smraw[SMSZ];
    us* sA = (us*)smraw;
    us* sB = sA + 2048;
    float (*TT)[BN + 4] = (float (*)[BN + 4])smraw;

    int t = threadIdx.x;
    int lane = t & 63, w = t >> 6;
    int lr = lane & 15, lq = lane >> 4;
    int m0 = blockIdx.x * 64, n0 = blockIdx.y * BN;
    int gA0 = blockIdx.x * 4;
    int gB0 = n0 >> 4;

    floatx4 acc[2][NJ];
    #pragma unroll
    for (int i = 0; i < 2; i++)
        #pragma unroll
        for (int j = 0; j < NJ; j++) acc[i][j] = (floatx4){0.f, 0.f, 0.f, 0.f};

    for (int ks = 0; ks * 32 < Kloop; ks++) {
        #pragma unroll
        for (int s = 0; s < PS; s++) {
            int slot = w * PS + s;
            if (slot < 4)
                g2lds16(Ap + ((size_t)(gA0 + slot) * KA + ks * 32) * 16 + lane * 8,
                        sA + slot * 512);
            else
                g2lds16(Bp + ((size_t)(gB0 + slot - 4) * KB + ks * 32) * 16 + lane * 8,
                        sB + (slot - 4) * 512);
        }
        __syncthreads();
        short8 af[2], bfv[NJ];
        #pragma unroll
        for (int i = 0; i < 2; i++)
            af[i] = *(const short8*)(sA + ((w & 1) * 2 + i) * 512 + lane * 8);
        #pragma unroll
        for (int j = 0; j < NJ; j++)
            bfv[j] = *(const short8*)(sB + ((w >> 1) * NJ + j) * 512 + lane * 8);
        #pragma unroll
        for (int i = 0; i < 2; i++)
            #pragma unroll
            for (int j = 0; j < NJ; j++)
                acc[i][j] = __builtin_amdgcn_mfma_f32_16x16x32_bf16(
                    af[i], bfv[j], acc[i][j], 0, 0, 0);
        __syncthreads();
    }

    #pragma unroll
    for (int i = 0; i < 2; i++)
        #pragma unroll
        for (int j = 0; j < NJ; j++)
            #pragma unroll
            for (int r = 0; r < 4; r++)
                TT[(w & 1) * 32 + i * 16 + lq * 4 + r]
                  [(w >> 1) * (BN / 2) + j * 16 + lr] = acc[i][j][r];
    __syncthreads();

    if (MODE == MO_F32_PACK || MODE == MO_SOFTPLUS) {
        constexpr int passes = 64 * BN / 4 / 256;
        #pragma unroll
        for (int p = 0; p < passes; p++) {
            int idx = p * 256 + t;
            int row = idx / (BN / 4);
            int c = (idx % (BN / 4)) * 4;
            float4 v = *(float4*)&TT[row][c];
            int col = n0 + c;
            size_t o = (size_t)(m0 + row) * ldc + col;
            float vv[4] = {v.x, v.y, v.z, v.w};
            float oo[4];
            #pragma unroll
            for (int e = 0; e < 4; e++) {
                if (MODE == MO_SOFTPLUS) {
                    float tb = vv[e] + bias[col + e];
                    oo[e] = (tb > 20.f) ? tb : log1pf(__expf(tb));
                } else {
                    oo[e] = vv[e];
                }
            }
            float4 ov = {oo[0], oo[1], oo[2], oo[3]};
            *(float4*)(outF + o) = ov;
        }
    }
    if (MODE == MO_F32_PACK) {
        constexpr int passes = 8 * BN / 256;
        #pragma unroll
        for (int p = 0; p < passes; p++) {
            int sig = p * 256 + t;
            int gi = sig / (2 * BN);
            int rem = sig % (2 * BN);
            int ksl = rem >> 6;
            int ln2 = rem & 63;
            int lr2 = ln2 & 15, lq2 = ln2 >> 4;
            short8 o8;
            #pragma unroll
            for (int e = 0; e < 8; e++)
                o8[e] = (short)f2bf(TT[gi * 16 + lr2][ksl * 32 + lq2 * 8 + e]);
            *(short8*)(outP + ((size_t)((m0 >> 4) + gi) * Nout + n0 + ksl * 32) * 16
                       + ln2 * 8) = o8;
        }
    }
}

// ---------------------------------------------------------------------------
// Depthwise conv (K=4, pad 1/2) + SiLU; writes packed xh / z and xh f32 rows.
// ---------------------------------------------------------------------------
__global__ __launch_bounds__(256) void conv_pk(
    const us* __restrict__ xz, const float* __restrict__ cwx,
    const float* __restrict__ cwz, float* __restrict__ xh_f,
    us* __restrict__ xh_p, us* __restrict__ outbuf_p)
{
    int bx = blockIdx.x, t = threadIdx.x;
    int b = bx >> 6, g = bx & 63;
    size_t rowbase = (size_t)b * LSEQ;
    #pragma unroll
    for (int s = 0; s < 4; s++) {
        int sig = t * 4 + s;
        int ks = sig >> 6, lane = sig & 63;
        int lr = lane & 15, lq = lane >> 4;
        int l = g * 16 + lr;
        int d0 = ks * 32 + lq * 8;
        float ax[8] = {0, 0, 0, 0, 0, 0, 0, 0};
        #pragma unroll
        for (int kk = 0; kk < 4; kk++) {
            int ls = l + kk - 1;
            if (ls >= 0 && ls < LSEQ) {
                const us* src = xz + (rowbase + ls) * DINNER + d0;
                #pragma unroll
                for (int e = 0; e < 8; e++)
                    ax[e] += cwx[(d0 + e) * 4 + kk] * bf2f(src[e]);
            }
        }
        short8 o8;
        float vo[8];
        #pragma unroll
        for (int e = 0; e < 8; e++) {
            float v = ax[e];
            v = v / (1.f + __expf(-v));
            vo[e] = v;
            o8[e] = (short)f2bf(v);
        }
        *(short8*)(xh_p + (size_t)bx * 8192 + sig * 8) = o8;
        float* fo = xh_f + (rowbase + l) * D2 + d0;
        float4 f0 = {vo[0], vo[1], vo[2], vo[3]};
        float4 f1 = {vo[4], vo[5], vo[6], vo[7]};
        *(float4*)fo = f0;
        *(float4*)(fo + 4) = f1;
    }
    #pragma unroll
    for (int s = 0; s < 4; s++) {
        int sig = t * 4 + s;
        int ks = sig >> 6, lane = sig & 63;
        int lr = lane & 15, lq = lane >> 4;
        int l = g * 16 + lr;
        int d0 = ks * 32 + lq * 8;
        float az[8] = {0, 0, 0, 0, 0, 0, 0, 0};
        #pragma unroll
        for (int kk = 0; kk < 4; kk++) {
            int ls = l + kk - 1;
            if (ls >= 0 && ls < LSEQ) {
                const us* src = xz + (rowbase + ls) * DINNER + 512 + d0;
                #pragma unroll
                for (int e = 0; e < 8; e++)
                    az[e] += cwz[(d0 + e) * 4 + kk] * bf2f(src[e]);
            }
        }
        short8 o8;
        #pragma unroll
        for (int e = 0; e < 8; e++) {
            float v = az[e];
            v = v / (1.f + __expf(-v));
            o8[e] = (short)f2bf(v);
        }
        *(short8*)(outbuf_p + (size_t)bx * 16384 + 8192 + sig * 8) = o8;
    }
}

// ---------------------------------------------------------------------------
// Selective scan, 3-phase chunked linear recurrence (phase3 writes packed y).
// ---------------------------------------------------------------------------
__global__ __launch_bounds__(256) void scan_phase1(
    const float* __restrict__ delta, const float* __restrict__ u,
    const float* __restrict__ xdbl, const float* __restrict__ A_log,
    float* __restrict__ S, float* __restrict__ P)
{
    int bx = blockIdx.x;
    int b = bx >> 5, rem = bx & 31, c = rem >> 1, half = rem & 1;
    int d = half * 256 + threadIdx.x;
    float A[NSTATE], h[NSTATE];
    #pragma unroll
    for (int n = 0; n < NSTATE; n++) {
        A[n] = -__expf(A_log[d * NSTATE + n]);
        h[n] = 0.f;
    }
    float sdt = 0.f;
    int l0 = c * LCHUNK;
    for (int l = l0; l < l0 + LCHUNK; ++l) {
        size_t idx = (size_t)(b * LSEQ + l);
        float dv = delta[idx * D2 + d];
        float uv = u[idx * D2 + d];
        float du = dv * uv;
        const float4* Bp = (const float4*)(xdbl + idx * 64 + 32);
        float4 B0 = Bp[0], B1 = Bp[1], B2 = Bp[2], B3 = Bp[3];
        float Bn[16] = {B0.x, B0.y, B0.z, B0.w, B1.x, B1.y, B1.z, B1.w,
                        B2.x, B2.y, B2.z, B2.w, B3.x, B3.y, B3.z, B3.w};
        sdt += dv;
        #pragma unroll
        for (int n = 0; n < NSTATE; n++)
            h[n] = __expf(dv * A[n]) * h[n] + du * Bn[n];
    }
    size_t o = ((size_t)(b * D2 + d)) * (NCHUNK * NSTATE) + c * NSTATE;
    #pragma unroll
    for (int n = 0; n < NSTATE; n++) {
        S[o + n] = h[n];
        P[o + n] = __expf(sdt * A[n]);
    }
}

__global__ __launch_bounds__(256) void scan_phase2(
    const float* __restrict__ S, const float* __restrict__ P,
    float* __restrict__ hin)
{
    int gid = blockIdx.x * 256 + threadIdx.x;
    int n = gid & 15;
    size_t base = ((size_t)(gid >> 4)) * (NCHUNK * NSTATE) + n;
    float h = 0.f;
    for (int c = 0; c < NCHUNK; c++) {
        size_t o = base + c * NSTATE;
        hin[o] = h;
        h = P[o] * h + S[o];
    }
}

__global__ __launch_bounds__(256) void scan_phase3(
    const float* __restrict__ delta, const float* __restrict__ u,
    const float* __restrict__ xdbl, const float* __restrict__ hin,
    const float* __restrict__ A_log, const float* __restrict__ Dvec,
    us* __restrict__ outbuf_p)
{
    int bx = blockIdx.x;
    int b = bx >> 5, rem = bx & 31, c = rem >> 1, half = rem & 1;
    int t = threadIdx.x;
    int d = half * 256 + t;
    __shared__ us yl[64][264];
    float A[NSTATE], h[NSTATE];
    size_t hb = ((size_t)(b * D2 + d)) * (NCHUNK * NSTATE) + c * NSTATE;
    #pragma unroll
    for (int n = 0; n < NSTATE; n++) {
        A[n] = -__expf(A_log[d * NSTATE + n]);
        h[n] = hin[hb + n];
    }
    float Dd = Dvec[d];
    int l0 = c * LCHUNK;
    for (int l = l0; l < l0 + LCHUNK; ++l) {
        size_t idx = (size_t)(b * LSEQ + l);
        float dv = delta[idx * D2 + d];
        float uv = u[idx * D2 + d];
        float du = dv * uv;
        const float4* Bp = (const float4*)(xdbl + idx * 64 + 32);
        const float4* Cp = (const float4*)(xdbl + idx * 64 + 48);
        float4 B0 = Bp[0], B1 = Bp[1], B2 = Bp[2], B3 = Bp[3];
        float4 C0 = Cp[0], C1 = Cp[1], C2 = Cp[2], C3 = Cp[3];
        float Bn[16] = {B0.x, B0.y, B0.z, B0.w, B1.x, B1.y, B1.z, B1.w,
                        B2.x, B2.y, B2.z, B2.w, B3.x, B3.y, B3.z, B3.w};
        float Cn[16] = {C0.x, C0.y, C0.z, C0.w, C1.x, C1.y, C1.z, C1.w,
                        C2.x, C2.y, C2.z, C2.w, C3.x, C3.y, C3.z, C3.w};
        float y = Dd * uv;
        #pragma unroll
        for (int n = 0; n < NSTATE; n++) {
            h[n] = __expf(dv * A[n]) * h[n] + du * Bn[n];
            y += h[n] * Cn[n];
        }
        yl[l - l0][t] = f2bf(y);
    }
    __syncthreads();
    int g0 = (b * LSEQ + l0) >> 4;
    #pragma unroll
    for (int s = 0; s < 8; s++) {
        int sig = t * 8 + s;
        int gi = sig >> 9;
        int rem2 = sig & 511;
        int ksl = rem2 >> 6;
        int lane = rem2 & 63;
        int lr = lane & 15, lq = lane >> 4;
        uint4 v = *(uint4*)&yl[gi * 16 + lr][ksl * 32 + lq * 8];
        *(uint4*)(outbuf_p + ((size_t)(g0 + gi) * 1024 + (half * 8 + ksl) * 32) * 16
                  + lane * 8) = v;
    }
}

// ---------------------------------------------------------------------------
// Host-side launch
// ---------------------------------------------------------------------------
extern "C" void kernel_launch(void* const* d_in, const int* in_sizes, int n_in,
                              void* d_out, int out_size, void* d_ws, size_t ws_size,
                              hipStream_t stream)
{
    const float* x         = (const float*)d_in[0];
    const float* ln1_w     = (const float*)d_in[1];
    const float* ln1_b     = (const float*)d_in[2];
    const float* in_proj_w = (const float*)d_in[3];
    const float* conv_x_w  = (const float*)d_in[4];
    const float* conv_z_w  = (const float*)d_in[5];
    const float* x_proj_w  = (const float*)d_in[6];
    const float* dt_proj_w = (const float*)d_in[7];
    const float* dt_proj_b = (const float*)d_in[8];
    const float* A_log     = (const float*)d_in[9];
    const float* ssm_D     = (const float*)d_in[10];
    const float* out_proj_w= (const float*)d_in[11];
    const float* ln2_w     = (const float*)d_in[12];
    const float* ln2_b     = (const float*)d_in[13];
    const float* fc1_w     = (const float*)d_in[14];
    const float* fc1_b     = (const float*)d_in[15];
    const float* fc2_w     = (const float*)d_in[16];
    const float* fc2_b     = (const float*)d_in[17];
    float* out = (float*)d_out;

    char* p = (char*)d_ws;
    us* wp_in  = (us*)(p);
    us* wp_x   = (us*)(p + 1048576);
    us* wp_dt  = (us*)(p + 1114112);
    us* wp_out = (us*)(p + 1146880);
    us* wp_f1  = (us*)(p + 2195456);
    us* wp_f2  = (us*)(p + 4292608);
    us*    xn_p    = (us*)(p + 6389760);
    us*    xz      = (us*)(p + 14778368);
    us*    xh_p    = (us*)(p + 31555584);
    float* xh_f    = (float*)(p + 39944192);
    us*    outbuf_p= (us*)(p + 56721408);
    float* xdbl_f  = (float*)(p + 73498624);
    us*    xdbl_p  = (us*)(p + 75595776);
    float* delta_f = (float*)(p + 76644352);
    float* scanS   = (float*)(p + 93421568);
    float* scanP   = (float*)(p + 97615872);
    float* hin     = (float*)(p + 101810176);
    float* h_f     = (float*)(p + 106004480);
    us*    h2_p    = xn_p;
    us*    mlp1_p  = xz;

    // 1. weights -> packed bf16
    cvt_pack6<<<1560, 256, 0, stream>>>(in_proj_w, x_proj_w, dt_proj_w,
        out_proj_w, fc1_w, fc2_w, wp_in, wp_x, wp_dt, wp_out, wp_f1, wp_f2);

    // 2. LN1 -> xn packed
    ln_pack<<<512, 256, 0, stream>>>(x, ln1_w, ln1_b, xn_p);

    // 3. in_proj (8192x1024, K=512) -> xz row-major bf16
    gemm_rd<MO_ROWBF16, 64><<<dim3(32, 16), 256, 0, stream>>>(
        xn_p, wp_in, 512, 0, DINNER, nullptr, xz, nullptr, nullptr, nullptr);

    // 4. conv + SiLU -> xh (f32 row + packed), z -> outbuf packed (k>=512)
    conv_pk<<<512, 256, 0, stream>>>(xz, conv_x_w, conv_z_w, xh_f, xh_p, outbuf_p);

    // 5. x_proj (8192x64, K=512) -> xdbl f32 row + packed bf16 (Kpack=64)
    gemm_pk<MO_F32_PACK, 64><<<dim3(128, 1), 256, 0, stream>>>(
        xh_p, 512, wp_x, 512, 512, 64, 64,
        xdbl_f, nullptr, xdbl_p, nullptr, nullptr);

    // 6. dt_proj (8192x512, K=32) + softplus -> delta f32 row-major
    gemm_pk<MO_SOFTPLUS, 64><<<dim3(128, 8), 256, 0, stream>>>(
        xdbl_p, 64, wp_dt, 32, 32, 0, D2,
        delta_f, nullptr, nullptr, dt_proj_b, nullptr);

    // 7-9. selective scan; phase3 writes y packed into outbuf (k<512)
    scan_phase1<<<256, 256, 0, stream>>>(delta_f, xh_f, xdbl_f, A_log, scanS, scanP);
    scan_phase2<<<256, 256, 0, stream>>>(scanS, scanP, hin);
    scan_phase3<<<512, 256, 0, stream>>>(delta_f, xh_f, xdbl_f, hin, A_log,
        ssm_D, outbuf_p);

    // 10. out_proj (8192x512, K=1024) + residual x -> h f32 row-major
    gemm_rd<MO_RES, 32><<<dim3(64, 8), 256, 0, stream>>>(
        outbuf_p, wp_out, 1024, 0, DMODEL, h_f, nullptr, nullptr, nullptr, x);

    // 11. LN2 -> h2 packed
    ln_pack<<<512, 256, 0, stream>>>(h_f, ln2_w, ln2_b, h2_p);

    // 12. fc1 (8192x2048, K=512) + bias + GELU -> mlp1 packed (Kpack=2048)
    gemm_rd<MO_GELU_PACK, 64><<<dim3(32, 32), 256, 0, stream>>>(
        h2_p, wp_f1, 512, HIDDEN, 0, nullptr, nullptr, mlp1_p, fc1_b, nullptr);

    // 13. fc2 (8192x512, K=2048) + bias + residual h -> d_out f32
    gemm_rd<MO_BIAS_RES, 32><<<dim3(64, 8), 256, 0, stream>>>(
        mlp1_p, wp_f2, 2048, 0, DMODEL, out, nullptr, nullptr, fc2_b, h_f);
}

// Round 8
// 344.297 us; speedup vs baseline: 1.3274x; 1.1172x over previous
//
#include <hip/hip_runtime.h>
#include <stdint.h>

// ---------------------------------------------------------------------------
// Mamba block on MI355X (gfx950).  B=8, L=1024, D_MODEL=512, D_INNER=1024,
// D2=512, DT_RANK=32, N_STATE=16, K_CONV=4, HIDDEN=2048.  M = B*L = 8192.
//
// R8 = R4 (best measured) + two gemm fixes:
//  - BK=64 staging per barrier round (2x MFMA per drain)
//  - epilogue in two 32-row half-passes -> LDS 24/16 KB -> 6-8 blocks/CU
// Packed operand layout: (m,k) -> (m/16)*16*K + (k/32)*512 + lane*8 + (k%8),
// lane = ((k>>3)&3)*16 + (m&15).  Staging = contiguous 1 KB global_load_lds.
// ---------------------------------------------------------------------------

#define MROWS 8192
#define LSEQ 1024
#define DMODEL 512
#define DINNER 1024
#define D2 512
#define NSTATE 16
#define HIDDEN 2048
#define NCHUNK 16
#define LCHUNK 64

typedef unsigned short us;
typedef short short8 __attribute__((ext_vector_type(8)));
typedef float floatx4 __attribute__((ext_vector_type(4)));

__device__ __forceinline__ us f2bf(float f) {
    unsigned int u = __float_as_uint(f);
    u = (u + 0x7fffu + ((u >> 16) & 1u)) >> 16;
    return (us)u;
}
__device__ __forceinline__ float bf2f(us u) {
    return __uint_as_float(((unsigned int)u) << 16);
}

__device__ __forceinline__ void g2lds16(const void* g, void* l) {
    typedef __attribute__((address_space(1))) void GV;
    typedef __attribute__((address_space(3))) void LV;
    GV* gp = (GV*)(uintptr_t)g;
    LV* lp = (LV*)(uint32_t)(uintptr_t)l;
    __builtin_amdgcn_global_load_lds(gp, lp, 16, 0, 0);
}

// ---------------------------------------------------------------------------
// Pack fp32 weight W(N,K) -> bf16 fragment order (one 16B slot per sig).
// ---------------------------------------------------------------------------
__device__ __forceinline__ void pack_slot(const float* __restrict__ w,
                                          us* __restrict__ dst, int K, int sig)
{
    int lane = sig & 63;
    int KS = K >> 5;
    int ks = (sig >> 6) % KS;
    int g = sig / (KS << 6);
    const float* src = w + (size_t)(g * 16 + (lane & 15)) * K
                         + ks * 32 + (lane >> 4) * 8;
    short8 o;
    #pragma unroll
    for (int e = 0; e < 8; e++) o[e] = (short)f2bf(src[e]);
    *(short8*)(dst + (size_t)sig * 8) = o;
}

__global__ __launch_bounds__(256) void cvt_pack6(
    const float* __restrict__ w0, const float* __restrict__ w1,
    const float* __restrict__ w2, const float* __restrict__ w3,
    const float* __restrict__ w4, const float* __restrict__ w5,
    us* __restrict__ o0, us* __restrict__ o1, us* __restrict__ o2,
    us* __restrict__ o3, us* __restrict__ o4, us* __restrict__ o5)
{
    int bx = blockIdx.x, t = threadIdx.x;
    if (bx < 256)        pack_slot(w0, o0, 512,  bx * 256 + t);
    else if (bx < 272)   pack_slot(w1, o1, 512,  (bx - 256) * 256 + t);
    else if (bx < 280)   pack_slot(w2, o2, 32,   (bx - 272) * 256 + t);
    else if (bx < 536)   pack_slot(w3, o3, 1024, (bx - 280) * 256 + t);
    else if (bx < 1048)  pack_slot(w4, o4, 512,  (bx - 536) * 256 + t);
    else                 pack_slot(w5, o5, 2048, (bx - 1048) * 256 + t);
}

// ---------------------------------------------------------------------------
// LayerNorm over 512 ch; one block per 16-row group; writes packed bf16.
// ---------------------------------------------------------------------------
__global__ __launch_bounds__(256) void ln_pack(
    const float* __restrict__ x, const float* __restrict__ w,
    const float* __restrict__ b, us* __restrict__ outp)
{
    int g = blockIdx.x, t = threadIdx.x;
    __shared__ float T[16][516];
    __shared__ float mu[16], rs[16];
    const float* src = x + (size_t)g * 16 * DMODEL;
    #pragma unroll
    for (int p = 0; p < 8; p++) {
        int idx4 = p * 256 + t;
        int row = idx4 >> 7, c = (idx4 & 127) << 2;
        float4 v = *(const float4*)(src + (size_t)row * DMODEL + c);
        *(float4*)&T[row][c] = v;
    }
    __syncthreads();
    int r = t >> 4, i = t & 15;
    float s = 0.f, ss = 0.f;
    #pragma unroll
    for (int c = 0; c < 32; c++) {
        float v = T[r][c * 16 + i];
        s += v; ss += v * v;
    }
    #pragma unroll
    for (int off = 8; off > 0; off >>= 1) {
        s += __shfl_down(s, off, 16);
        ss += __shfl_down(ss, off, 16);
    }
    if (i == 0) {
        float m = s * (1.f / DMODEL);
        mu[r] = m;
        rs[r] = rsqrtf(ss * (1.f / DMODEL) - m * m + 1e-5f);
    }
    __syncthreads();
    #pragma unroll
    for (int s0 = 0; s0 < 4; s0++) {
        int sig = t * 4 + s0;
        int lane = sig & 63, ks = sig >> 6;
        int lr = lane & 15, lq = lane >> 4;
        int k0 = ks * 32 + lq * 8;
        float m = mu[lr], r2 = rs[lr];
        short8 o;
        #pragma unroll
        for (int e = 0; e < 8; e++)
            o[e] = (short)f2bf((T[lr][k0 + e] - m) * r2 * w[k0 + e] + b[k0 + e]);
        *(short8*)(outp + (size_t)g * 8192 + sig * 8) = o;
    }
}

#define MO_ROWBF16 0
#define MO_F32_PACK 1
#define MO_SOFTPLUS 2
#define MO_RES 3
#define MO_GELU_PACK 4
#define MO_BIAS_RES 5

// ---------------------------------------------------------------------------
// gemm_pk2: BM=64 x BN, BK=64 per barrier round, 4 waves.
// Wave tile 32 x BN/2; 2*2*(BN/32) MFMAs per wave per round.
// LDS: staging (8 + 2*BN/16) KB, unioned with 32-row TT transpose.
// K must be a multiple of 64.
// ---------------------------------------------------------------------------
template <int MODE, int BN>
__global__ __launch_bounds__(256) void gemm_pk2(
    const us* __restrict__ Ap, const us* __restrict__ Bp, int K,
    int Nout, int ldc,
    float* __restrict__ outF, us* __restrict__ outB, us* __restrict__ outP,
    const float* __restrict__ bias, const float* __restrict__ res)
{
    constexpr int NBg = BN / 16;          // B 16-col groups
    constexpr int NJ = BN / 32;           // col-tiles per wave
    constexpr int TS = 8 + 2 * NBg;       // staging slots (1 KB each)
    constexpr int PS = TS / 4;            // slots per wave
    constexpr int STG = TS * 1024;
    constexpr int TTS = 32 * (BN + 4) * 4;
    constexpr int SM = STG > TTS ? STG : TTS;
    __shared__ __align__(16) char smraw[SM];
    us* sA = (us*)smraw;                  // 8 slots: g*2+kl
    us* sB = sA + 8 * 512;                // 2*NBg slots: j*2+kl
    float (*TT)[BN + 4] = (float (*)[BN + 4])smraw;

    int t = threadIdx.x;
    int lane = t & 63, w = t >> 6;
    int lr = lane & 15, lq = lane >> 4;
    int m0 = blockIdx.x * 64, n0 = blockIdx.y * BN;
    int gA0 = blockIdx.x * 4;
    int gB0 = blockIdx.y * NBg;
    int KS32 = K >> 5;

    floatx4 acc[2][NJ];
    #pragma unroll
    for (int i = 0; i < 2; i++)
        #pragma unroll
        for (int j = 0; j < NJ; j++) acc[i][j] = (floatx4){0.f, 0.f, 0.f, 0.f};

    for (int k64 = 0; k64 * 64 < K; k64++) {
        #pragma unroll
        for (int s = 0; s < PS; s++) {
            int slot = w * PS + s;
            if (slot < 8) {
                int g = slot >> 1, kl = slot & 1;
                g2lds16(Ap + ((size_t)(gA0 + g) * KS32 + k64 * 2 + kl) * 512
                           + lane * 8,
                        sA + slot * 512);
            } else {
                int sl = slot - 8;
                int j = sl >> 1, kl = sl & 1;
                g2lds16(Bp + ((size_t)(gB0 + j) * KS32 + k64 * 2 + kl) * 512
                           + lane * 8,
                        sB + sl * 512);
            }
        }
        __syncthreads();
        #pragma unroll
        for (int kl = 0; kl < 2; kl++) {
            short8 af[2], bfv[NJ];
            #pragma unroll
            for (int i = 0; i < 2; i++)
                af[i] = *(const short8*)(sA + (((w & 1) * 2 + i) * 2 + kl) * 512
                                         + lane * 8);
            #pragma unroll
            for (int j = 0; j < NJ; j++)
                bfv[j] = *(const short8*)(sB + (((w >> 1) * NJ + j) * 2 + kl) * 512
                                          + lane * 8);
            #pragma unroll
            for (int i = 0; i < 2; i++)
                #pragma unroll
                for (int j = 0; j < NJ; j++)
                    acc[i][j] = __builtin_amdgcn_mfma_f32_16x16x32_bf16(
                        af[i], bfv[j], acc[i][j], 0, 0, 0);
        }
        __syncthreads();
    }

    // ---- epilogue: two 32-row half-passes through TT ----
    #pragma unroll
    for (int h = 0; h < 2; h++) {
        if ((w & 1) == h) {
            #pragma unroll
            for (int i = 0; i < 2; i++)
                #pragma unroll
                for (int j = 0; j < NJ; j++)
                    #pragma unroll
                    for (int r = 0; r < 4; r++)
                        TT[i * 16 + lq * 4 + r]
                          [(w >> 1) * (BN / 2) + j * 16 + lr] = acc[i][j][r];
        }
        __syncthreads();

        if (MODE == MO_ROWBF16) {
            constexpr int passes = 32 * BN / 8 / 256;
            #pragma unroll
            for (int p = 0; p < passes; p++) {
                int idx = p * 256 + t;
                int row = idx / (BN / 8);
                int c = (idx % (BN / 8)) * 8;
                short8 o8;
                #pragma unroll
                for (int e = 0; e < 8; e++) o8[e] = (short)f2bf(TT[row][c + e]);
                *(short8*)(outB + (size_t)(m0 + h * 32 + row) * ldc + n0 + c) = o8;
            }
        }
        if (MODE == MO_F32_PACK || MODE == MO_RES || MODE == MO_BIAS_RES) {
            constexpr int passes = 32 * BN / 4 / 256;
            #pragma unroll
            for (int p = 0; p < passes; p++) {
                int idx = p * 256 + t;
                int row = idx / (BN / 4);
                int c = (idx % (BN / 4)) * 4;
                float4 v = *(float4*)&TT[row][c];
                int col = n0 + c;
                size_t o = (size_t)(m0 + h * 32 + row) * ldc + col;
                float4 ov;
                if (MODE == MO_RES) {
                    float4 rv = *(const float4*)(res + o);
                    ov.x = v.x + rv.x; ov.y = v.y + rv.y;
                    ov.z = v.z + rv.z; ov.w = v.w + rv.w;
                } else if (MODE == MO_BIAS_RES) {
                    float4 rv = *(const float4*)(res + o);
                    float4 bv = *(const float4*)(bias + col);
                    ov.x = v.x + bv.x + rv.x; ov.y = v.y + bv.y + rv.y;
                    ov.z = v.z + bv.z + rv.z; ov.w = v.w + bv.w + rv.w;
                } else {
                    ov = v;
                }
                *(float4*)(outF + o) = ov;
            }
        }
        if (MODE == MO_F32_PACK || MODE == MO_GELU_PACK) {
            constexpr int passes = 4 * BN / 256;
            #pragma unroll
            for (int p = 0; p < passes; p++) {
                int sig = p * 256 + t;
                int gi = sig / (2 * BN);
                int rem = sig % (2 * BN);
                int ksl = rem >> 6;
                int ln2 = rem & 63;
                int lr2 = ln2 & 15, lq2 = ln2 >> 4;
                short8 o8;
                #pragma unroll
                for (int e = 0; e < 8; e++) {
                    float vv = TT[gi * 16 + lr2][ksl * 32 + lq2 * 8 + e];
                    if (MODE == MO_GELU_PACK) {
                        float tb = vv + bias[n0 + ksl * 32 + lq2 * 8 + e];
                        vv = 0.5f * tb * (1.f + erff(tb * 0.70710678118f));
                    }
                    o8[e] = (short)f2bf(vv);
                }
                *(short8*)(outP + ((size_t)((m0 >> 4) + h * 2 + gi) * Nout
                           + n0 + ksl * 32) * 16 + ln2 * 8) = o8;
            }
        }
        __syncthreads();
    }
}

// ---------------------------------------------------------------------------
// gemm_pk (R4, BK=32): dt_proj only (K=32).
// ---------------------------------------------------------------------------
template <int MODE, int BN>
__global__ __launch_bounds__(256) void gemm_pk(
    const us* __restrict__ Ap, int KA,
    const us* __restrict__ Bp, int KB, int Kloop,
    int Nout, int ldc,
    float* __restrict__ outF, us* __restrict__ outB, us* __restrict__ outP,
    const float* __restrict__ bias, const float* __restrict__ res)
{
    constexpr int NBg = BN / 16;
    constexpr int NJ = BN / 32;
    constexpr int TS = 4 + NBg;
    constexpr int PS = TS / 4;
    constexpr int SMSZ = 64 * (BN + 4) * 4;
    __shared__ __align__(16) char smraw[SMSZ];
    us* sA = (us*)smraw;
    us* sB = sA + 2048;
    float (*TT)[BN + 4] = (float (*)[BN + 4])smraw;

    int t = threadIdx.x;
    int lane = t & 63, w = t >> 6;
    int lr = lane & 15, lq = lane >> 4;
    int m0 = blockIdx.x * 64, n0 = blockIdx.y * BN;
    int gA0 = blockIdx.x * 4;
    int gB0 = n0 >> 4;

    floatx4 acc[2][NJ];
    #pragma unroll
    for (int i = 0; i < 2; i++)
        #pragma unroll
        for (int j = 0; j < NJ; j++) acc[i][j] = (floatx4){0.f, 0.f, 0.f, 0.f};

    for (int ks = 0; ks * 32 < Kloop; ks++) {
        #pragma unroll
        for (int s = 0; s < PS; s++) {
            int slot = w * PS + s;
            if (slot < 4)
                g2lds16(Ap + ((size_t)(gA0 + slot) * KA + ks * 32) * 16 + lane * 8,
                        sA + slot * 512);
            else
                g2lds16(Bp + ((size_t)(gB0 + slot - 4) * KB + ks * 32) * 16 + lane * 8,
                        sB + (slot - 4) * 512);
        }
        __syncthreads();
        short8 af[2], bfv[NJ];
        #pragma unroll
        for (int i = 0; i < 2; i++)
            af[i] = *(const short8*)(sA + ((w & 1) * 2 + i) * 512 + lane * 8);
        #pragma unroll
        for (int j = 0; j < NJ; j++)
            bfv[j] = *(const short8*)(sB + ((w >> 1) * NJ + j) * 512 + lane * 8);
        #pragma unroll
        for (int i = 0; i < 2; i++)
            #pragma unroll
            for (int j = 0; j < NJ; j++)
                acc[i][j] = __builtin_amdgcn_mfma_f32_16x16x32_bf16(
                    af[i], bfv[j], acc[i][j], 0, 0, 0);
        __syncthreads();
    }

    #pragma unroll
    for (int i = 0; i < 2; i++)
        #pragma unroll
        for (int j = 0; j < NJ; j++)
            #pragma unroll
            for (int r = 0; r < 4; r++)
                TT[(w & 1) * 32 + i * 16 + lq * 4 + r]
                  [(w >> 1) * (BN / 2) + j * 16 + lr] = acc[i][j][r];
    __syncthreads();

    if (MODE == MO_SOFTPLUS) {
        constexpr int passes = 64 * BN / 4 / 256;
        #pragma unroll
        for (int p = 0; p < passes; p++) {
            int idx = p * 256 + t;
            int row = idx / (BN / 4);
            int c = (idx % (BN / 4)) * 4;
            float4 v = *(float4*)&TT[row][c];
            int col = n0 + c;
            size_t o = (size_t)(m0 + row) * ldc + col;
            float vv[4] = {v.x, v.y, v.z, v.w};
            float oo[4];
            #pragma unroll
            for (int e = 0; e < 4; e++) {
                float tb = vv[e] + bias[col + e];
                oo[e] = (tb > 20.f) ? tb : log1pf(__expf(tb));
            }
            float4 ov = {oo[0], oo[1], oo[2], oo[3]};
            *(float4*)(outF + o) = ov;
        }
    }
}

// ---------------------------------------------------------------------------
// Depthwise conv (K=4, pad 1/2) + SiLU; writes packed xh / z and xh f32 rows.
// ---------------------------------------------------------------------------
__global__ __launch_bounds__(256) void conv_pk(
    const us* __restrict__ xz, const float* __restrict__ cwx,
    const float* __restrict__ cwz, float* __restrict__ xh_f,
    us* __restrict__ xh_p, us* __restrict__ outbuf_p)
{
    int bx = blockIdx.x, t = threadIdx.x;
    int b = bx >> 6, g = bx & 63;
    size_t rowbase = (size_t)b * LSEQ;
    #pragma unroll
    for (int s = 0; s < 4; s++) {
        int sig = t * 4 + s;
        int ks = sig >> 6, lane = sig & 63;
        int lr = lane & 15, lq = lane >> 4;
        int l = g * 16 + lr;
        int d0 = ks * 32 + lq * 8;
        float ax[8] = {0, 0, 0, 0, 0, 0, 0, 0};
        #pragma unroll
        for (int kk = 0; kk < 4; kk++) {
            int ls = l + kk - 1;
            if (ls >= 0 && ls < LSEQ) {
                const us* src = xz + (rowbase + ls) * DINNER + d0;
                #pragma unroll
                for (int e = 0; e < 8; e++)
                    ax[e] += cwx[(d0 + e) * 4 + kk] * bf2f(src[e]);
            }
        }
        short8 o8;
        float vo[8];
        #pragma unroll
        for (int e = 0; e < 8; e++) {
            float v = ax[e];
            v = v / (1.f + __expf(-v));
            vo[e] = v;
            o8[e] = (short)f2bf(v);
        }
        *(short8*)(xh_p + (size_t)bx * 8192 + sig * 8) = o8;
        float* fo = xh_f + (rowbase + l) * D2 + d0;
        float4 f0 = {vo[0], vo[1], vo[2], vo[3]};
        float4 f1 = {vo[4], vo[5], vo[6], vo[7]};
        *(float4*)fo = f0;
        *(float4*)(fo + 4) = f1;
    }
    #pragma unroll
    for (int s = 0; s < 4; s++) {
        int sig = t * 4 + s;
        int ks = sig >> 6, lane = sig & 63;
        int lr = lane & 15, lq = lane >> 4;
        int l = g * 16 + lr;
        int d0 = ks * 32 + lq * 8;
        float az[8] = {0, 0, 0, 0, 0, 0, 0, 0};
        #pragma unroll
        for (int kk = 0; kk < 4; kk++) {
            int ls = l + kk - 1;
            if (ls >= 0 && ls < LSEQ) {
                const us* src = xz + (rowbase + ls) * DINNER + 512 + d0;
                #pragma unroll
                for (int e = 0; e < 8; e++)
                    az[e] += cwz[(d0 + e) * 4 + kk] * bf2f(src[e]);
            }
        }
        short8 o8;
        #pragma unroll
        for (int e = 0; e < 8; e++) {
            float v = az[e];
            v = v / (1.f + __expf(-v));
            o8[e] = (short)f2bf(v);
        }
        *(short8*)(outbuf_p + (size_t)bx * 16384 + 8192 + sig * 8) = o8;
    }
}

// ---------------------------------------------------------------------------
// Selective scan, 3-phase chunked linear recurrence (phase3 writes packed y).
// ---------------------------------------------------------------------------
__global__ __launch_bounds__(256) void scan_phase1(
    const float* __restrict__ delta, const float* __restrict__ u,
    const float* __restrict__ xdbl, const float* __restrict__ A_log,
    float* __restrict__ S, float* __restrict__ P)
{
    int bx = blockIdx.x;
    int b = bx >> 5, rem = bx & 31, c = rem >> 1, half = rem & 1;
    int d = half * 256 + threadIdx.x;
    float A[NSTATE], h[NSTATE];
    #pragma unroll
    for (int n = 0; n < NSTATE; n++) {
        A[n] = -__expf(A_log[d * NSTATE + n]);
        h[n] = 0.f;
    }
    float sdt = 0.f;
    int l0 = c * LCHUNK;
    for (int l = l0; l < l0 + LCHUNK; ++l) {
        size_t idx = (size_t)(b * LSEQ + l);
        float dv = delta[idx * D2 + d];
        float uv = u[idx * D2 + d];
        float du = dv * uv;
        const float4* Bp = (const float4*)(xdbl + idx * 64 + 32);
        float4 B0 = Bp[0], B1 = Bp[1], B2 = Bp[2], B3 = Bp[3];
        float Bn[16] = {B0.x, B0.y, B0.z, B0.w, B1.x, B1.y, B1.z, B1.w,
                        B2.x, B2.y, B2.z, B2.w, B3.x, B3.y, B3.z, B3.w};
        sdt += dv;
        #pragma unroll
        for (int n = 0; n < NSTATE; n++)
            h[n] = __expf(dv * A[n]) * h[n] + du * Bn[n];
    }
    size_t o = ((size_t)(b * D2 + d)) * (NCHUNK * NSTATE) + c * NSTATE;
    #pragma unroll
    for (int n = 0; n < NSTATE; n++) {
        S[o + n] = h[n];
        P[o + n] = __expf(sdt * A[n]);
    }
}

__global__ __launch_bounds__(256) void scan_phase2(
    const float* __restrict__ S, const float* __restrict__ P,
    float* __restrict__ hin)
{
    int gid = blockIdx.x * 256 + threadIdx.x;
    int n = gid & 15;
    size_t base = ((size_t)(gid >> 4)) * (NCHUNK * NSTATE) + n;
    float h = 0.f;
    for (int c = 0; c < NCHUNK; c++) {
        size_t o = base + c * NSTATE;
        hin[o] = h;
        h = P[o] * h + S[o];
    }
}

__global__ __launch_bounds__(256) void scan_phase3(
    const float* __restrict__ delta, const float* __restrict__ u,
    const float* __restrict__ xdbl, const float* __restrict__ hin,
    const float* __restrict__ A_log, const float* __restrict__ Dvec,
    us* __restrict__ outbuf_p)
{
    int bx = blockIdx.x;
    int b = bx >> 5, rem = bx & 31, c = rem >> 1, half = rem & 1;
    int t = threadIdx.x;
    int d = half * 256 + t;
    __shared__ us yl[64][264];
    float A[NSTATE], h[NSTATE];
    size_t hb = ((size_t)(b * D2 + d)) * (NCHUNK * NSTATE) + c * NSTATE;
    #pragma unroll
    for (int n = 0; n < NSTATE; n++) {
        A[n] = -__expf(A_log[d * NSTATE + n]);
        h[n] = hin[hb + n];
    }
    float Dd = Dvec[d];
    int l0 = c * LCHUNK;
    for (int l = l0; l < l0 + LCHUNK; ++l) {
        size_t idx = (size_t)(b * LSEQ + l);
        float dv = delta[idx * D2 + d];
        float uv = u[idx * D2 + d];
        float du = dv * uv;
        const float4* Bp = (const float4*)(xdbl + idx * 64 + 32);
        const float4* Cp = (const float4*)(xdbl + idx * 64 + 48);
        float4 B0 = Bp[0], B1 = Bp[1], B2 = Bp[2], B3 = Bp[3];
        float4 C0 = Cp[0], C1 = Cp[1], C2 = Cp[2], C3 = Cp[3];
        float Bn[16] = {B0.x, B0.y, B0.z, B0.w, B1.x, B1.y, B1.z, B1.w,
                        B2.x, B2.y, B2.z, B2.w, B3.x, B3.y, B3.z, B3.w};
        float Cn[16] = {C0.x, C0.y, C0.z, C0.w, C1.x, C1.y, C1.z, C1.w,
                        C2.x, C2.y, C2.z, C2.w, C3.x, C3.y, C3.z, C3.w};
        float y = Dd * uv;
        #pragma unroll
        for (int n = 0; n < NSTATE; n++) {
            h[n] = __expf(dv * A[n]) * h[n] + du * Bn[n];
            y += h[n] * Cn[n];
        }
        yl[l - l0][t] = f2bf(y);
    }
    __syncthreads();
    int g0 = (b * LSEQ + l0) >> 4;
    #pragma unroll
    for (int s = 0; s < 8; s++) {
        int sig = t * 8 + s;
        int gi = sig >> 9;
        int rem2 = sig & 511;
        int ksl = rem2 >> 6;
        int lane = rem2 & 63;
        int lr = lane & 15, lq = lane >> 4;
        uint4 v = *(uint4*)&yl[gi * 16 + lr][ksl * 32 + lq * 8];
        *(uint4*)(outbuf_p + ((size_t)(g0 + gi) * 1024 + (half * 8 + ksl) * 32) * 16
                  + lane * 8) = v;
    }
}

// ---------------------------------------------------------------------------
// Host-side launch
// ---------------------------------------------------------------------------
extern "C" void kernel_launch(void* const* d_in, const int* in_sizes, int n_in,
                              void* d_out, int out_size, void* d_ws, size_t ws_size,
                              hipStream_t stream)
{
    const float* x         = (const float*)d_in[0];
    const float* ln1_w     = (const float*)d_in[1];
    const float* ln1_b     = (const float*)d_in[2];
    const float* in_proj_w = (const float*)d_in[3];
    const float* conv_x_w  = (const float*)d_in[4];
    const float* conv_z_w  = (const float*)d_in[5];
    const float* x_proj_w  = (const float*)d_in[6];
    const float* dt_proj_w = (const float*)d_in[7];
    const float* dt_proj_b = (const float*)d_in[8];
    const float* A_log     = (const float*)d_in[9];
    const float* ssm_D     = (const float*)d_in[10];
    const float* out_proj_w= (const float*)d_in[11];
    const float* ln2_w     = (const float*)d_in[12];
    const float* ln2_b     = (const float*)d_in[13];
    const float* fc1_w     = (const float*)d_in[14];
    const float* fc1_b     = (const float*)d_in[15];
    const float* fc2_w     = (const float*)d_in[16];
    const float* fc2_b     = (const float*)d_in[17];
    float* out = (float*)d_out;

    char* p = (char*)d_ws;
    us* wp_in  = (us*)(p);
    us* wp_x   = (us*)(p + 1048576);
    us* wp_dt  = (us*)(p + 1114112);
    us* wp_out = (us*)(p + 1146880);
    us* wp_f1  = (us*)(p + 2195456);
    us* wp_f2  = (us*)(p + 4292608);
    us*    xn_p    = (us*)(p + 6389760);
    us*    xz      = (us*)(p + 14778368);
    us*    xh_p    = (us*)(p + 31555584);
    float* xh_f    = (float*)(p + 39944192);
    us*    outbuf_p= (us*)(p + 56721408);
    float* xdbl_f  = (float*)(p + 73498624);
    us*    xdbl_p  = (us*)(p + 75595776);
    float* delta_f = (float*)(p + 76644352);
    float* scanS   = (float*)(p + 93421568);
    float* scanP   = (float*)(p + 97615872);
    float* hin     = (float*)(p + 101810176);
    float* h_f     = (float*)(p + 106004480);
    us*    h2_p    = xn_p;
    us*    mlp1_p  = xz;

    // 1. weights -> packed bf16
    cvt_pack6<<<1560, 256, 0, stream>>>(in_proj_w, x_proj_w, dt_proj_w,
        out_proj_w, fc1_w, fc2_w, wp_in, wp_x, wp_dt, wp_out, wp_f1, wp_f2);

    // 2. LN1 -> xn packed
    ln_pack<<<512, 256, 0, stream>>>(x, ln1_w, ln1_b, xn_p);

    // 3. in_proj (8192x1024, K=512) -> xz row-major bf16
    gemm_pk2<MO_ROWBF16, 128><<<dim3(128, 8), 256, 0, stream>>>(
        xn_p, wp_in, 512, 0, DINNER, nullptr, xz, nullptr, nullptr, nullptr);

    // 4. conv + SiLU -> xh (f32 row + packed), z -> outbuf packed (k>=512)
    conv_pk<<<512, 256, 0, stream>>>(xz, conv_x_w, conv_z_w, xh_f, xh_p, outbuf_p);

    // 5. x_proj (8192x64, K=512) -> xdbl f32 row + packed bf16 (Kpack=64)
    gemm_pk2<MO_F32_PACK, 64><<<dim3(128, 1), 256, 0, stream>>>(
        xh_p, wp_x, 512, 64, 64, xdbl_f, nullptr, xdbl_p, nullptr, nullptr);

    // 6. dt_proj (8192x512, K=32) + softplus -> delta f32 row-major
    gemm_pk<MO_SOFTPLUS, 64><<<dim3(128, 8), 256, 0, stream>>>(
        xdbl_p, 64, wp_dt, 32, 32, 0, D2,
        delta_f, nullptr, nullptr, dt_proj_b, nullptr);

    // 7-9. selective scan; phase3 writes y packed into outbuf (k<512)
    scan_phase1<<<256, 256, 0, stream>>>(delta_f, xh_f, xdbl_f, A_log, scanS, scanP);
    scan_phase2<<<256, 256, 0, stream>>>(scanS, scanP, hin);
    scan_phase3<<<512, 256, 0, stream>>>(delta_f, xh_f, xdbl_f, hin, A_log,
        ssm_D, outbuf_p);

    // 10. out_proj (8192x512, K=1024) + residual x -> h f32 row-major
    gemm_pk2<MO_RES, 64><<<dim3(128, 8), 256, 0, stream>>>(
        outbuf_p, wp_out, 1024, 0, DMODEL, h_f, nullptr, nullptr, nullptr, x);

    // 11. LN2 -> h2 packed
    ln_pack<<<512, 256, 0, stream>>>(h_f, ln2_w, ln2_b, h2_p);

    // 12. fc1 (8192x2048, K=512) + bias + GELU -> mlp1 packed (Kpack=2048)
    gemm_pk2<MO_GELU_PACK, 128><<<dim3(128, 16), 256, 0, stream>>>(
        h2_p, wp_f1, 512, HIDDEN, 0, nullptr, nullptr, mlp1_p, fc1_b, nullptr);

    // 13. fc2 (8192x512, K=2048) + bias + residual h -> d_out f32
    gemm_pk2<MO_BIAS_RES, 64><<<dim3(128, 8), 256, 0, stream>>>(
        mlp1_p, wp_f2, 2048, 0, DMODEL, out, nullptr, nullptr, fc2_b, h_f);
}

// Round 9
// 328.748 us; speedup vs baseline: 1.3902x; 1.0473x over previous
//
#include <hip/hip_runtime.h>
#include <stdint.h>

// ---------------------------------------------------------------------------
// Mamba block on MI355X (gfx950).  B=8, L=1024, D_MODEL=512, D_INNER=1024,
// D2=512, DT_RANK=32, N_STATE=16, K_CONV=4, HIDDEN=2048.  M = B*L = 8192.
//
// R9 = R8 + scan rewrite:
//  - phase1/phase3 grid-decode bug fixed (R4-R8 launched 512 blocks against a
//    256-block decode: half the grid computed b in [8,15] garbage)
//  - NCHUNK=32 (LCHUNK=32): 512 real blocks -> 2 waves/SIMD latency overlap
//  - exp2f with pre-scaled A2[n] = A[n]*log2(e)
//  - S/P/hin live in dead xz/xn_p regions (no workspace growth)
//  - out_proj / fc2 upgraded to BN=128 (16 MFMA/wave/barrier)
// GEMM operand layout: (m,k) -> (m/16)*16*K + (k/32)*512 + lane*8 + (k%8),
// lane = ((k>>3)&3)*16 + (m&15).  Staging = contiguous 1 KB global_load_lds.
// ---------------------------------------------------------------------------

#define MROWS 8192
#define LSEQ 1024
#define DMODEL 512
#define DINNER 1024
#define D2 512
#define NSTATE 16
#define HIDDEN 2048
#define NCHUNK 32
#define LCHUNK 32

typedef unsigned short us;
typedef short short8 __attribute__((ext_vector_type(8)));
typedef float floatx4 __attribute__((ext_vector_type(4)));

__device__ __forceinline__ us f2bf(float f) {
    unsigned int u = __float_as_uint(f);
    u = (u + 0x7fffu + ((u >> 16) & 1u)) >> 16;
    return (us)u;
}
__device__ __forceinline__ float bf2f(us u) {
    return __uint_as_float(((unsigned int)u) << 16);
}

__device__ __forceinline__ void g2lds16(const void* g, void* l) {
    typedef __attribute__((address_space(1))) void GV;
    typedef __attribute__((address_space(3))) void LV;
    GV* gp = (GV*)(uintptr_t)g;
    LV* lp = (LV*)(uint32_t)(uintptr_t)l;
    __builtin_amdgcn_global_load_lds(gp, lp, 16, 0, 0);
}

// ---------------------------------------------------------------------------
// Pack fp32 weight W(N,K) -> bf16 fragment order (one 16B slot per sig).
// ---------------------------------------------------------------------------
__device__ __forceinline__ void pack_slot(const float* __restrict__ w,
                                          us* __restrict__ dst, int K, int sig)
{
    int lane = sig & 63;
    int KS = K >> 5;
    int ks = (sig >> 6) % KS;
    int g = sig / (KS << 6);
    const float* src = w + (size_t)(g * 16 + (lane & 15)) * K
                         + ks * 32 + (lane >> 4) * 8;
    short8 o;
    #pragma unroll
    for (int e = 0; e < 8; e++) o[e] = (short)f2bf(src[e]);
    *(short8*)(dst + (size_t)sig * 8) = o;
}

__global__ __launch_bounds__(256) void cvt_pack6(
    const float* __restrict__ w0, const float* __restrict__ w1,
    const float* __restrict__ w2, const float* __restrict__ w3,
    const float* __restrict__ w4, const float* __restrict__ w5,
    us* __restrict__ o0, us* __restrict__ o1, us* __restrict__ o2,
    us* __restrict__ o3, us* __restrict__ o4, us* __restrict__ o5)
{
    int bx = blockIdx.x, t = threadIdx.x;
    if (bx < 256)        pack_slot(w0, o0, 512,  bx * 256 + t);
    else if (bx < 272)   pack_slot(w1, o1, 512,  (bx - 256) * 256 + t);
    else if (bx < 280)   pack_slot(w2, o2, 32,   (bx - 272) * 256 + t);
    else if (bx < 536)   pack_slot(w3, o3, 1024, (bx - 280) * 256 + t);
    else if (bx < 1048)  pack_slot(w4, o4, 512,  (bx - 536) * 256 + t);
    else                 pack_slot(w5, o5, 2048, (bx - 1048) * 256 + t);
}

// ---------------------------------------------------------------------------
// LayerNorm over 512 ch; one block per 16-row group; writes packed bf16.
// ---------------------------------------------------------------------------
__global__ __launch_bounds__(256) void ln_pack(
    const float* __restrict__ x, const float* __restrict__ w,
    const float* __restrict__ b, us* __restrict__ outp)
{
    int g = blockIdx.x, t = threadIdx.x;
    __shared__ float T[16][516];
    __shared__ float mu[16], rs[16];
    const float* src = x + (size_t)g * 16 * DMODEL;
    #pragma unroll
    for (int p = 0; p < 8; p++) {
        int idx4 = p * 256 + t;
        int row = idx4 >> 7, c = (idx4 & 127) << 2;
        float4 v = *(const float4*)(src + (size_t)row * DMODEL + c);
        *(float4*)&T[row][c] = v;
    }
    __syncthreads();
    int r = t >> 4, i = t & 15;
    float s = 0.f, ss = 0.f;
    #pragma unroll
    for (int c = 0; c < 32; c++) {
        float v = T[r][c * 16 + i];
        s += v; ss += v * v;
    }
    #pragma unroll
    for (int off = 8; off > 0; off >>= 1) {
        s += __shfl_down(s, off, 16);
        ss += __shfl_down(ss, off, 16);
    }
    if (i == 0) {
        float m = s * (1.f / DMODEL);
        mu[r] = m;
        rs[r] = rsqrtf(ss * (1.f / DMODEL) - m * m + 1e-5f);
    }
    __syncthreads();
    #pragma unroll
    for (int s0 = 0; s0 < 4; s0++) {
        int sig = t * 4 + s0;
        int lane = sig & 63, ks = sig >> 6;
        int lr = lane & 15, lq = lane >> 4;
        int k0 = ks * 32 + lq * 8;
        float m = mu[lr], r2 = rs[lr];
        short8 o;
        #pragma unroll
        for (int e = 0; e < 8; e++)
            o[e] = (short)f2bf((T[lr][k0 + e] - m) * r2 * w[k0 + e] + b[k0 + e]);
        *(short8*)(outp + (size_t)g * 8192 + sig * 8) = o;
    }
}

#define MO_ROWBF16 0
#define MO_F32_PACK 1
#define MO_SOFTPLUS 2
#define MO_RES 3
#define MO_GELU_PACK 4
#define MO_BIAS_RES 5

// ---------------------------------------------------------------------------
// gemm_pk2: BM=64 x BN, BK=64 per barrier round, 4 waves.
// ---------------------------------------------------------------------------
template <int MODE, int BN>
__global__ __launch_bounds__(256) void gemm_pk2(
    const us* __restrict__ Ap, const us* __restrict__ Bp, int K,
    int Nout, int ldc,
    float* __restrict__ outF, us* __restrict__ outB, us* __restrict__ outP,
    const float* __restrict__ bias, const float* __restrict__ res)
{
    constexpr int NBg = BN / 16;
    constexpr int NJ = BN / 32;
    constexpr int TS = 8 + 2 * NBg;
    constexpr int PS = TS / 4;
    constexpr int STG = TS * 1024;
    constexpr int TTS = 32 * (BN + 4) * 4;
    constexpr int SM = STG > TTS ? STG : TTS;
    __shared__ __align__(16) char smraw[SM];
    us* sA = (us*)smraw;
    us* sB = sA + 8 * 512;
    float (*TT)[BN + 4] = (float (*)[BN + 4])smraw;

    int t = threadIdx.x;
    int lane = t & 63, w = t >> 6;
    int lr = lane & 15, lq = lane >> 4;
    int m0 = blockIdx.x * 64, n0 = blockIdx.y * BN;
    int gA0 = blockIdx.x * 4;
    int gB0 = blockIdx.y * NBg;
    int KS32 = K >> 5;

    floatx4 acc[2][NJ];
    #pragma unroll
    for (int i = 0; i < 2; i++)
        #pragma unroll
        for (int j = 0; j < NJ; j++) acc[i][j] = (floatx4){0.f, 0.f, 0.f, 0.f};

    for (int k64 = 0; k64 * 64 < K; k64++) {
        #pragma unroll
        for (int s = 0; s < PS; s++) {
            int slot = w * PS + s;
            if (slot < 8) {
                int g = slot >> 1, kl = slot & 1;
                g2lds16(Ap + ((size_t)(gA0 + g) * KS32 + k64 * 2 + kl) * 512
                           + lane * 8,
                        sA + slot * 512);
            } else {
                int sl = slot - 8;
                int j = sl >> 1, kl = sl & 1;
                g2lds16(Bp + ((size_t)(gB0 + j) * KS32 + k64 * 2 + kl) * 512
                           + lane * 8,
                        sB + sl * 512);
            }
        }
        __syncthreads();
        #pragma unroll
        for (int kl = 0; kl < 2; kl++) {
            short8 af[2], bfv[NJ];
            #pragma unroll
            for (int i = 0; i < 2; i++)
                af[i] = *(const short8*)(sA + (((w & 1) * 2 + i) * 2 + kl) * 512
                                         + lane * 8);
            #pragma unroll
            for (int j = 0; j < NJ; j++)
                bfv[j] = *(const short8*)(sB + (((w >> 1) * NJ + j) * 2 + kl) * 512
                                          + lane * 8);
            #pragma unroll
            for (int i = 0; i < 2; i++)
                #pragma unroll
                for (int j = 0; j < NJ; j++)
                    acc[i][j] = __builtin_amdgcn_mfma_f32_16x16x32_bf16(
                        af[i], bfv[j], acc[i][j], 0, 0, 0);
        }
        __syncthreads();
    }

    #pragma unroll
    for (int h = 0; h < 2; h++) {
        if ((w & 1) == h) {
            #pragma unroll
            for (int i = 0; i < 2; i++)
                #pragma unroll
                for (int j = 0; j < NJ; j++)
                    #pragma unroll
                    for (int r = 0; r < 4; r++)
                        TT[i * 16 + lq * 4 + r]
                          [(w >> 1) * (BN / 2) + j * 16 + lr] = acc[i][j][r];
        }
        __syncthreads();

        if (MODE == MO_ROWBF16) {
            constexpr int passes = 32 * BN / 8 / 256;
            #pragma unroll
            for (int p = 0; p < passes; p++) {
                int idx = p * 256 + t;
                int row = idx / (BN / 8);
                int c = (idx % (BN / 8)) * 8;
                short8 o8;
                #pragma unroll
                for (int e = 0; e < 8; e++) o8[e] = (short)f2bf(TT[row][c + e]);
                *(short8*)(outB + (size_t)(m0 + h * 32 + row) * ldc + n0 + c) = o8;
            }
        }
        if (MODE == MO_F32_PACK || MODE == MO_RES || MODE == MO_BIAS_RES) {
            constexpr int passes = 32 * BN / 4 / 256;
            #pragma unroll
            for (int p = 0; p < passes; p++) {
                int idx = p * 256 + t;
                int row = idx / (BN / 4);
                int c = (idx % (BN / 4)) * 4;
                float4 v = *(float4*)&TT[row][c];
                int col = n0 + c;
                size_t o = (size_t)(m0 + h * 32 + row) * ldc + col;
                float4 ov;
                if (MODE == MO_RES) {
                    float4 rv = *(const float4*)(res + o);
                    ov.x = v.x + rv.x; ov.y = v.y + rv.y;
                    ov.z = v.z + rv.z; ov.w = v.w + rv.w;
                } else if (MODE == MO_BIAS_RES) {
                    float4 rv = *(const float4*)(res + o);
                    float4 bv = *(const float4*)(bias + col);
                    ov.x = v.x + bv.x + rv.x; ov.y = v.y + bv.y + rv.y;
                    ov.z = v.z + bv.z + rv.z; ov.w = v.w + bv.w + rv.w;
                } else {
                    ov = v;
                }
                *(float4*)(outF + o) = ov;
            }
        }
        if (MODE == MO_F32_PACK || MODE == MO_GELU_PACK) {
            constexpr int passes = 4 * BN / 256;
            #pragma unroll
            for (int p = 0; p < passes; p++) {
                int sig = p * 256 + t;
                int gi = sig / (2 * BN);
                int rem = sig % (2 * BN);
                int ksl = rem >> 6;
                int ln2 = rem & 63;
                int lr2 = ln2 & 15, lq2 = ln2 >> 4;
                short8 o8;
                #pragma unroll
                for (int e = 0; e < 8; e++) {
                    float vv = TT[gi * 16 + lr2][ksl * 32 + lq2 * 8 + e];
                    if (MODE == MO_GELU_PACK) {
                        float tb = vv + bias[n0 + ksl * 32 + lq2 * 8 + e];
                        vv = 0.5f * tb * (1.f + erff(tb * 0.70710678118f));
                    }
                    o8[e] = (short)f2bf(vv);
                }
                *(short8*)(outP + ((size_t)((m0 >> 4) + h * 2 + gi) * Nout
                           + n0 + ksl * 32) * 16 + ln2 * 8) = o8;
            }
        }
        __syncthreads();
    }
}

// ---------------------------------------------------------------------------
// gemm_pk (BK=32): dt_proj only (K=32).
// ---------------------------------------------------------------------------
template <int MODE, int BN>
__global__ __launch_bounds__(256) void gemm_pk(
    const us* __restrict__ Ap, int KA,
    const us* __restrict__ Bp, int KB, int Kloop,
    int Nout, int ldc,
    float* __restrict__ outF, us* __restrict__ outB, us* __restrict__ outP,
    const float* __restrict__ bias, const float* __restrict__ res)
{
    constexpr int NBg = BN / 16;
    constexpr int NJ = BN / 32;
    constexpr int TS = 4 + NBg;
    constexpr int PS = TS / 4;
    constexpr int SMSZ = 64 * (BN + 4) * 4;
    __shared__ __align__(16) char smraw[SMSZ];
    us* sA = (us*)smraw;
    us* sB = sA + 2048;
    float (*TT)[BN + 4] = (float (*)[BN + 4])smraw;

    int t = threadIdx.x;
    int lane = t & 63, w = t >> 6;
    int lr = lane & 15, lq = lane >> 4;
    int m0 = blockIdx.x * 64, n0 = blockIdx.y * BN;
    int gA0 = blockIdx.x * 4;
    int gB0 = n0 >> 4;

    floatx4 acc[2][NJ];
    #pragma unroll
    for (int i = 0; i < 2; i++)
        #pragma unroll
        for (int j = 0; j < NJ; j++) acc[i][j] = (floatx4){0.f, 0.f, 0.f, 0.f};

    for (int ks = 0; ks * 32 < Kloop; ks++) {
        #pragma unroll
        for (int s = 0; s < PS; s++) {
            int slot = w * PS + s;
            if (slot < 4)
                g2lds16(Ap + ((size_t)(gA0 + slot) * KA + ks * 32) * 16 + lane * 8,
                        sA + slot * 512);
            else
                g2lds16(Bp + ((size_t)(gB0 + slot - 4) * KB + ks * 32) * 16 + lane * 8,
                        sB + (slot - 4) * 512);
        }
        __syncthreads();
        short8 af[2], bfv[NJ];
        #pragma unroll
        for (int i = 0; i < 2; i++)
            af[i] = *(const short8*)(sA + ((w & 1) * 2 + i) * 512 + lane * 8);
        #pragma unroll
        for (int j = 0; j < NJ; j++)
            bfv[j] = *(const short8*)(sB + ((w >> 1) * NJ + j) * 512 + lane * 8);
        #pragma unroll
        for (int i = 0; i < 2; i++)
            #pragma unroll
            for (int j = 0; j < NJ; j++)
                acc[i][j] = __builtin_amdgcn_mfma_f32_16x16x32_bf16(
                    af[i], bfv[j], acc[i][j], 0, 0, 0);
        __syncthreads();
    }

    #pragma unroll
    for (int i = 0; i < 2; i++)
        #pragma unroll
        for (int j = 0; j < NJ; j++)
            #pragma unroll
            for (int r = 0; r < 4; r++)
                TT[(w & 1) * 32 + i * 16 + lq * 4 + r]
                  [(w >> 1) * (BN / 2) + j * 16 + lr] = acc[i][j][r];
    __syncthreads();

    if (MODE == MO_SOFTPLUS) {
        constexpr int passes = 64 * BN / 4 / 256;
        #pragma unroll
        for (int p = 0; p < passes; p++) {
            int idx = p * 256 + t;
            int row = idx / (BN / 4);
            int c = (idx % (BN / 4)) * 4;
            float4 v = *(float4*)&TT[row][c];
            int col = n0 + c;
            size_t o = (size_t)(m0 + row) * ldc + col;
            float vv[4] = {v.x, v.y, v.z, v.w};
            float oo[4];
            #pragma unroll
            for (int e = 0; e < 4; e++) {
                float tb = vv[e] + bias[col + e];
                oo[e] = (tb > 20.f) ? tb : log1pf(__expf(tb));
            }
            float4 ov = {oo[0], oo[1], oo[2], oo[3]};
            *(float4*)(outF + o) = ov;
        }
    }
}

// ---------------------------------------------------------------------------
// Depthwise conv (K=4, pad 1/2) + SiLU; writes packed xh / z and xh f32 rows.
// ---------------------------------------------------------------------------
__global__ __launch_bounds__(256) void conv_pk(
    const us* __restrict__ xz, const float* __restrict__ cwx,
    const float* __restrict__ cwz, float* __restrict__ xh_f,
    us* __restrict__ xh_p, us* __restrict__ outbuf_p)
{
    int bx = blockIdx.x, t = threadIdx.x;
    int b = bx >> 6, g = bx & 63;
    size_t rowbase = (size_t)b * LSEQ;
    #pragma unroll
    for (int s = 0; s < 4; s++) {
        int sig = t * 4 + s;
        int ks = sig >> 6, lane = sig & 63;
        int lr = lane & 15, lq = lane >> 4;
        int l = g * 16 + lr;
        int d0 = ks * 32 + lq * 8;
        float ax[8] = {0, 0, 0, 0, 0, 0, 0, 0};
        #pragma unroll
        for (int kk = 0; kk < 4; kk++) {
            int ls = l + kk - 1;
            if (ls >= 0 && ls < LSEQ) {
                const us* src = xz + (rowbase + ls) * DINNER + d0;
                #pragma unroll
                for (int e = 0; e < 8; e++)
                    ax[e] += cwx[(d0 + e) * 4 + kk] * bf2f(src[e]);
            }
        }
        short8 o8;
        float vo[8];
        #pragma unroll
        for (int e = 0; e < 8; e++) {
            float v = ax[e];
            v = v / (1.f + __expf(-v));
            vo[e] = v;
            o8[e] = (short)f2bf(v);
        }
        *(short8*)(xh_p + (size_t)bx * 8192 + sig * 8) = o8;
        float* fo = xh_f + (rowbase + l) * D2 + d0;
        float4 f0 = {vo[0], vo[1], vo[2], vo[3]};
        float4 f1 = {vo[4], vo[5], vo[6], vo[7]};
        *(float4*)fo = f0;
        *(float4*)(fo + 4) = f1;
    }
    #pragma unroll
    for (int s = 0; s < 4; s++) {
        int sig = t * 4 + s;
        int ks = sig >> 6, lane = sig & 63;
        int lr = lane & 15, lq = lane >> 4;
        int l = g * 16 + lr;
        int d0 = ks * 32 + lq * 8;
        float az[8] = {0, 0, 0, 0, 0, 0, 0, 0};
        #pragma unroll
        for (int kk = 0; kk < 4; kk++) {
            int ls = l + kk - 1;
            if (ls >= 0 && ls < LSEQ) {
                const us* src = xz + (rowbase + ls) * DINNER + 512 + d0;
                #pragma unroll
                for (int e = 0; e < 8; e++)
                    az[e] += cwz[(d0 + e) * 4 + kk] * bf2f(src[e]);
            }
        }
        short8 o8;
        #pragma unroll
        for (int e = 0; e < 8; e++) {
            float v = az[e];
            v = v / (1.f + __expf(-v));
            o8[e] = (short)f2bf(v);
        }
        *(short8*)(outbuf_p + (size_t)bx * 16384 + 8192 + sig * 8) = o8;
    }
}

// ---------------------------------------------------------------------------
// Selective scan, 3-phase chunked linear recurrence.  NCHUNK=32, LCHUNK=32.
// Grids: phase1/phase3 = 8b * 32c * 2half = 512 blocks (decode matches!).
// ---------------------------------------------------------------------------
__global__ __launch_bounds__(256) void scan_phase1(
    const float* __restrict__ delta, const float* __restrict__ u,
    const float* __restrict__ xdbl, const float* __restrict__ A_log,
    float* __restrict__ S, float* __restrict__ P)
{
    int bx = blockIdx.x;                 // 512
    int b = bx >> 6, rem = bx & 63, c = rem >> 1, half = rem & 1;
    int d = half * 256 + threadIdx.x;
    float A2[NSTATE], h[NSTATE];
    #pragma unroll
    for (int n = 0; n < NSTATE; n++) {
        A2[n] = -__expf(A_log[d * NSTATE + n]) * 1.44269504f;
        h[n] = 0.f;
    }
    float sdt = 0.f;
    int l0 = c * LCHUNK;
    for (int l = l0; l < l0 + LCHUNK; ++l) {
        size_t idx = (size_t)(b * LSEQ + l);
        float dv = delta[idx * D2 + d];
        float uv = u[idx * D2 + d];
        float du = dv * uv;
        const float4* Bp = (const float4*)(xdbl + idx * 64 + 32);
        float4 B0 = Bp[0], B1 = Bp[1], B2 = Bp[2], B3 = Bp[3];
        float Bn[16] = {B0.x, B0.y, B0.z, B0.w, B1.x, B1.y, B1.z, B1.w,
                        B2.x, B2.y, B2.z, B2.w, B3.x, B3.y, B3.z, B3.w};
        sdt += dv;
        #pragma unroll
        for (int n = 0; n < NSTATE; n++)
            h[n] = exp2f(dv * A2[n]) * h[n] + du * Bn[n];
    }
    size_t o = ((size_t)(b * D2 + d)) * (NCHUNK * NSTATE) + c * NSTATE;
    #pragma unroll
    for (int n = 0; n < NSTATE; n++) {
        S[o + n] = h[n];
        P[o + n] = exp2f(sdt * A2[n]);
    }
}

__global__ __launch_bounds__(256) void scan_phase2(
    const float* __restrict__ S, const float* __restrict__ P,
    float* __restrict__ hin)
{
    int gid = blockIdx.x * 256 + threadIdx.x;   // 65536 = 8*512*16
    int n = gid & 15;
    size_t base = ((size_t)(gid >> 4)) * (NCHUNK * NSTATE) + n;
    float h = 0.f;
    for (int c = 0; c < NCHUNK; c++) {
        size_t o = base + c * NSTATE;
        hin[o] = h;
        h = P[o] * h + S[o];
    }
}

__global__ __launch_bounds__(256) void scan_phase3(
    const float* __restrict__ delta, const float* __restrict__ u,
    const float* __restrict__ xdbl, const float* __restrict__ hin,
    const float* __restrict__ A_log, const float* __restrict__ Dvec,
    us* __restrict__ outbuf_p)
{
    int bx = blockIdx.x;                 // 512
    int b = bx >> 6, rem = bx & 63, c = rem >> 1, half = rem & 1;
    int t = threadIdx.x;
    int d = half * 256 + t;
    __shared__ us yl[LCHUNK][264];
    float A2[NSTATE], h[NSTATE];
    size_t hb = ((size_t)(b * D2 + d)) * (NCHUNK * NSTATE) + c * NSTATE;
    #pragma unroll
    for (int n = 0; n < NSTATE; n++) {
        A2[n] = -__expf(A_log[d * NSTATE + n]) * 1.44269504f;
        h[n] = hin[hb + n];
    }
    float Dd = Dvec[d];
    int l0 = c * LCHUNK;
    for (int l = l0; l < l0 + LCHUNK; ++l) {
        size_t idx = (size_t)(b * LSEQ + l);
        float dv = delta[idx * D2 + d];
        float uv = u[idx * D2 + d];
        float du = dv * uv;
        const float4* Bp = (const float4*)(xdbl + idx * 64 + 32);
        const float4* Cp = (const float4*)(xdbl + idx * 64 + 48);
        float4 B0 = Bp[0], B1 = Bp[1], B2 = Bp[2], B3 = Bp[3];
        float4 C0 = Cp[0], C1 = Cp[1], C2 = Cp[2], C3 = Cp[3];
        float Bn[16] = {B0.x, B0.y, B0.z, B0.w, B1.x, B1.y, B1.z, B1.w,
                        B2.x, B2.y, B2.z, B2.w, B3.x, B3.y, B3.z, B3.w};
        float Cn[16] = {C0.x, C0.y, C0.z, C0.w, C1.x, C1.y, C1.z, C1.w,
                        C2.x, C2.y, C2.z, C2.w, C3.x, C3.y, C3.z, C3.w};
        float y = Dd * uv;
        #pragma unroll
        for (int n = 0; n < NSTATE; n++) {
            h[n] = exp2f(dv * A2[n]) * h[n] + du * Bn[n];
            y += h[n] * Cn[n];
        }
        yl[l - l0][t] = f2bf(y);
    }
    __syncthreads();
    // packed write: 2 groups of 16 rows, k-range [half*256, half*256+256)
    int g0 = (b * LSEQ + l0) >> 4;
    #pragma unroll
    for (int s = 0; s < 4; s++) {
        int sig = t * 4 + s;                 // 0..1023
        int gi = sig >> 9;
        int rem2 = sig & 511;
        int ksl = rem2 >> 6;
        int lane = rem2 & 63;
        int lr = lane & 15, lq = lane >> 4;
        uint4 v = *(uint4*)&yl[gi * 16 + lr][ksl * 32 + lq * 8];
        *(uint4*)(outbuf_p + ((size_t)(g0 + gi) * 1024 + (half * 8 + ksl) * 32) * 16
                  + lane * 8) = v;
    }
}

// ---------------------------------------------------------------------------
// Host-side launch
// ---------------------------------------------------------------------------
extern "C" void kernel_launch(void* const* d_in, const int* in_sizes, int n_in,
                              void* d_out, int out_size, void* d_ws, size_t ws_size,
                              hipStream_t stream)
{
    const float* x         = (const float*)d_in[0];
    const float* ln1_w     = (const float*)d_in[1];
    const float* ln1_b     = (const float*)d_in[2];
    const float* in_proj_w = (const float*)d_in[3];
    const float* conv_x_w  = (const float*)d_in[4];
    const float* conv_z_w  = (const float*)d_in[5];
    const float* x_proj_w  = (const float*)d_in[6];
    const float* dt_proj_w = (const float*)d_in[7];
    const float* dt_proj_b = (const float*)d_in[8];
    const float* A_log     = (const float*)d_in[9];
    const float* ssm_D     = (const float*)d_in[10];
    const float* out_proj_w= (const float*)d_in[11];
    const float* ln2_w     = (const float*)d_in[12];
    const float* ln2_b     = (const float*)d_in[13];
    const float* fc1_w     = (const float*)d_in[14];
    const float* fc1_b     = (const float*)d_in[15];
    const float* fc2_w     = (const float*)d_in[16];
    const float* fc2_b     = (const float*)d_in[17];
    float* out = (float*)d_out;

    char* p = (char*)d_ws;
    us* wp_in  = (us*)(p);
    us* wp_x   = (us*)(p + 1048576);
    us* wp_dt  = (us*)(p + 1114112);
    us* wp_out = (us*)(p + 1146880);
    us* wp_f1  = (us*)(p + 2195456);
    us* wp_f2  = (us*)(p + 4292608);
    us*    xn_p    = (us*)(p + 6389760);      // 8 MB (hin overlays during scan)
    us*    xz      = (us*)(p + 14778368);     // 16 MB (scanS/scanP overlay; mlp1)
    us*    xh_p    = (us*)(p + 31555584);
    float* xh_f    = (float*)(p + 39944192);
    us*    outbuf_p= (us*)(p + 56721408);
    float* xdbl_f  = (float*)(p + 73498624);
    us*    xdbl_p  = (us*)(p + 75595776);
    float* delta_f = (float*)(p + 76644352);
    float* h_f     = (float*)(p + 106004480);
    us*    h2_p    = xn_p;
    us*    mlp1_p  = xz;
    // scan scratch overlays (xz dead after conv; xn_p dead until LN2):
    float* scanS = (float*)(p + 14778368);            // 8 MB
    float* scanP = (float*)(p + 14778368 + 8388608);  // 8 MB
    float* hin   = (float*)(p + 6389760);             // 8 MB

    // 1. weights -> packed bf16
    cvt_pack6<<<1560, 256, 0, stream>>>(in_proj_w, x_proj_w, dt_proj_w,
        out_proj_w, fc1_w, fc2_w, wp_in, wp_x, wp_dt, wp_out, wp_f1, wp_f2);

    // 2. LN1 -> xn packed
    ln_pack<<<512, 256, 0, stream>>>(x, ln1_w, ln1_b, xn_p);

    // 3. in_proj (8192x1024, K=512) -> xz row-major bf16
    gemm_pk2<MO_ROWBF16, 128><<<dim3(128, 8), 256, 0, stream>>>(
        xn_p, wp_in, 512, 0, DINNER, nullptr, xz, nullptr, nullptr, nullptr);

    // 4. conv + SiLU -> xh (f32 row + packed), z -> outbuf packed (k>=512)
    conv_pk<<<512, 256, 0, stream>>>(xz, conv_x_w, conv_z_w, xh_f, xh_p, outbuf_p);

    // 5. x_proj (8192x64, K=512) -> xdbl f32 row + packed bf16 (Kpack=64)
    gemm_pk2<MO_F32_PACK, 64><<<dim3(128, 1), 256, 0, stream>>>(
        xh_p, wp_x, 512, 64, 64, xdbl_f, nullptr, xdbl_p, nullptr, nullptr);

    // 6. dt_proj (8192x512, K=32) + softplus -> delta f32 row-major
    gemm_pk<MO_SOFTPLUS, 64><<<dim3(128, 8), 256, 0, stream>>>(
        xdbl_p, 64, wp_dt, 32, 32, 0, D2,
        delta_f, nullptr, nullptr, dt_proj_b, nullptr);

    // 7-9. selective scan (scan scratch overlays xz / xn_p)
    scan_phase1<<<512, 256, 0, stream>>>(delta_f, xh_f, xdbl_f, A_log, scanS, scanP);
    scan_phase2<<<256, 256, 0, stream>>>(scanS, scanP, hin);
    scan_phase3<<<512, 256, 0, stream>>>(delta_f, xh_f, xdbl_f, hin, A_log,
        ssm_D, outbuf_p);

    // 10. out_proj (8192x512, K=1024) + residual x -> h f32 row-major
    gemm_pk2<MO_RES, 128><<<dim3(128, 4), 256, 0, stream>>>(
        outbuf_p, wp_out, 1024, 0, DMODEL, h_f, nullptr, nullptr, nullptr, x);

    // 11. LN2 -> h2 packed
    ln_pack<<<512, 256, 0, stream>>>(h_f, ln2_w, ln2_b, h2_p);

    // 12. fc1 (8192x2048, K=512) + bias + GELU -> mlp1 packed (Kpack=2048)
    gemm_pk2<MO_GELU_PACK, 128><<<dim3(128, 16), 256, 0, stream>>>(
        h2_p, wp_f1, 512, HIDDEN, 0, nullptr, nullptr, mlp1_p, fc1_b, nullptr);

    // 13. fc2 (8192x512, K=2048) + bias + residual h -> d_out f32
    gemm_pk2<MO_BIAS_RES, 128><<<dim3(128, 4), 256, 0, stream>>>(
        mlp1_p, wp_f2, 2048, 0, DMODEL, out, nullptr, nullptr, fc2_b, h_f);
}